// Round 14
// baseline (492.189 us; speedup 1.0000x reference)
//
#include <hip/hip_runtime.h>

// ---------------------------------------------------------------------------
// MixtralAttention on MI355X (gfx950)
// B=2, S=2048, HID=4096, NH=32, NKV=8, HD=128, WINDOW=1024, THETA=10000
// Both GEMMs now use the BK=32 / 2-blocks-per-CU single-sync structure
// (the only schedule lever that A/B-verified positive this session):
//   GEMM1: tile 256x192 (NIF=3), grid 512, LDS 56 KB -> 2 blocks/CU
//   GEMM2: tile 256x128 (NIF=2), grid 512, LDS 48 KB -> 2-3 blocks/CU
// Per K-tile: { vmcnt(0); s_barrier; stage(t+1); NIF*8 MFMA }; latency is
// hidden by cross-block overlap (m114), not manual pipelining.
// NOTE: SQ_LDS_BANK_CONFLICT ~2.3e7 in these kernels is the inherent
// 1024B-per-gload_lds write serialization (counter matched arithmetic in
// R13 post-mortem), NOT a read conflict — do not chase it.
// ---------------------------------------------------------------------------

typedef __attribute__((ext_vector_type(8))) short short8;       // bf16x8 frag
typedef __attribute__((ext_vector_type(4))) float f32x4;        // 16x16 acc
typedef __attribute__((ext_vector_type(16))) float f32x16;      // 32x32 acc
typedef __attribute__((ext_vector_type(4))) unsigned int u32x4; // 16B load
typedef __attribute__((ext_vector_type(4))) unsigned short u16x4;

__device__ __forceinline__ unsigned short f2bf(float f) {
  unsigned int u = __builtin_bit_cast(unsigned int, f);
  u = u + 0x7fffu + ((u >> 16) & 1u);   // round-to-nearest-even
  return (unsigned short)(u >> 16);
}
__device__ __forceinline__ float bf2f(unsigned short h) {
  unsigned int u = ((unsigned int)h) << 16;
  return __builtin_bit_cast(float, u);
}
__device__ __forceinline__ unsigned int cvtpk_bf16(float lo, float hi) {
  unsigned int r;
  asm("v_cvt_pk_bf16_f32 %0, %1, %2" : "=v"(r) : "v"(lo), "v"(hi));
  return r;
}

__device__ __forceinline__ void gload_lds16(const unsigned short* g, unsigned short* l) {
  __builtin_amdgcn_global_load_lds(
      (const __attribute__((address_space(1))) unsigned int*)g,
      (__attribute__((address_space(3))) unsigned int*)l, 16, 0, 0);
}

#define MFMA16(A, B, C) __builtin_amdgcn_mfma_f32_16x16x32_bf16((A), (B), (C), 0, 0, 0)
#define MFMA32(A, B, C) __builtin_amdgcn_mfma_f32_32x32x16_bf16((A), (B), (C), 0, 0, 0)
#define BC8(x) __builtin_bit_cast(short8, (x))

// ---------------------------------------------------------------------------
// merged: cvt_t(wqkv -> wqkvT) + cvt_plain(hs -> hsb)
// ---------------------------------------------------------------------------
__global__ __launch_bounds__(256) void cvt1(const float* __restrict__ hs,
                                            const float* __restrict__ wqkv,
                                            unsigned short* __restrict__ hsb,
                                            unsigned short* __restrict__ wT) {
  const int bid = blockIdx.x;
  if (bid < 24576) {
    __shared__ float t[32][33];
    const int c0 = (bid % 192) * 32, r0 = (bid / 192) * 32;  // R=4096, C=6144
    const int tx = threadIdx.x & 31, ty = threadIdx.x >> 5;
#pragma unroll
    for (int i = 0; i < 4; ++i)
      t[ty + i * 8][tx] = wqkv[(size_t)(r0 + ty + i * 8) * 6144 + c0 + tx];
    __syncthreads();
#pragma unroll
    for (int i = 0; i < 4; ++i)
      wT[(size_t)(c0 + ty + i * 8) * 4096 + r0 + tx] = f2bf(t[tx][ty + i * 8]);
  } else {
    const int i = ((bid - 24576) * 256 + threadIdx.x) * 4;
    f32x4 v = *(const f32x4*)(hs + i);
    u16x4 o;
#pragma unroll
    for (int j = 0; j < 4; ++j) o[j] = f2bf(v[j]);
    *(u16x4*)(hsb + i) = o;
  }
}

// ---------------------------------------------------------------------------
// merged: rope_k (K heads in qkv) + cvt_t(wo -> woT)
// ---------------------------------------------------------------------------
__global__ __launch_bounds__(256) void rope_cvtwo(unsigned short* __restrict__ qkv,
                                                  const int* __restrict__ pos,
                                                  const float* __restrict__ wo,
                                                  unsigned short* __restrict__ wT) {
  const int bid = blockIdx.x;
  if (bid < 8192) {
    const int idx = bid * 256 + threadIdx.x;   // < 4096*8*64
    const int d = idx & 63;
    const int hh = (idx >> 6) & 7;
    const int tok = idx >> 9;
    const int s = tok & 2047;
    unsigned short* p = qkv + (size_t)tok * 6144 + 4096 + hh * 128 + d;
    const float x1 = bf2f(p[0]);
    const float x2 = bf2f(p[64]);
    const float inv = exp2f(-(float)d * 0.2076205059304601f);
    const float ang = (float)pos[s] * inv;
    const float c = cosf(ang), sn = sinf(ang);
    p[0]  = f2bf(x1 * c - x2 * sn);
    p[64] = f2bf(x2 * c + x1 * sn);
  } else {
    __shared__ float t[32][33];
    const int b2 = bid - 8192;
    const int c0 = (b2 % 128) * 32, r0 = (b2 / 128) * 32;   // R=C=4096
    const int tx = threadIdx.x & 31, ty = threadIdx.x >> 5;
#pragma unroll
    for (int i = 0; i < 4; ++i)
      t[ty + i * 8][tx] = wo[(size_t)(r0 + ty + i * 8) * 4096 + c0 + tx];
    __syncthreads();
#pragma unroll
    for (int i = 0; i < 4; ++i)
      wT[(size_t)(c0 + ty + i * 8) * 4096 + r0 + tx] = f2bf(t[tx][ty + i * 8]);
  }
}

// ---------------------------------------------------------------------------
// GEMM (both): C[M,N] = A[M,K] * B^T[N,K], tile 256 x (NIF*64), BK=32.
// LDS 2 x (8192 + NIF*2048) elems; 8 waves (2M x 4N); per-wave 128 x NIF*16.
// Staging per wave: A rows {w*16, 128+w*16}; B rows {w*16} (+{128+w*16} for
// w<4 when NIF==3). Linear dest, linear source (R12-measured best).
// Per K-tile: { vmcnt(0); s_barrier; stage(t+1); NIF*8 MFMA }.
// Grid 1D = 512 (both), bijective XCD swizzle, M-fastest within chunk.
// ---------------------------------------------------------------------------
template <int NIF, int OUTF32>
__global__ __launch_bounds__(512, 4) void gemm_k32(const unsigned short* __restrict__ A,
                                                   const unsigned short* __restrict__ BT,
                                                   void* __restrict__ Cout,
                                                   int M, int N, int K) {
  constexpr int BUFE = 8192 + NIF * 2048;
  __shared__ __align__(16) unsigned short lds[2][BUFE];
  const int tid = threadIdx.x;
  const int lane = tid & 63;
  const int w = tid >> 6;          // wave 0..7
  const int wr = w >> 2;           // 0..1 (M)
  const int wc = w & 3;            // 0..3 (N)
  const int g = lane >> 4;
  const int l15 = lane & 15;

  const int nwg = gridDim.x;
  const int cpx = nwg >> 3;
  const int bid = blockIdx.x;
  const int swz = (bid & 7) * cpx + (bid >> 3);
  const int MT = M >> 8;
  const int m0 = (swz % MT) * 256;
  const int n0 = (swz / MT) * (NIF * 64);

  // staging: lane covers row (lane>>2), 16B chunk (lane&3) -- linear
  const int lr = lane >> 2;          // 0..15
  const int lq = (lane & 3) * 8;     // 0,8,16,24 (elems)
  const unsigned short* Asrc = A + (size_t)(m0 + lr) * K + lq;
  const unsigned short* Bsrc = BT + (size_t)(n0 + lr) * K + lq;

  f32x4 acc[8][NIF] = {};

  auto stage = [&](int buf, int t) {
    const int tc = t * 32;
    gload_lds16(Asrc + (size_t)(w * 16) * K + tc, &lds[buf][w * 512]);
    gload_lds16(Asrc + (size_t)(128 + w * 16) * K + tc, &lds[buf][4096 + w * 512]);
    gload_lds16(Bsrc + (size_t)(w * 16) * K + tc, &lds[buf][8192 + w * 512]);
    if constexpr (NIF == 3) {
      if (w < 4)
        gload_lds16(Bsrc + (size_t)(128 + w * 16) * K + tc,
                    &lds[buf][12288 + w * 512]);
    }
  };
  auto rdA = [&](int buf, int mi) {
    const int row = wr * 128 + mi * 16 + l15;
    return *(const u32x4*)&lds[buf][row * 32 + g * 8];
  };
  auto rdB = [&](int buf, int ni) {
    const int row = wc * (NIF * 16) + ni * 16 + l15;
    return *(const u32x4*)&lds[buf][8192 + row * 32 + g * 8];
  };

  stage(0, 0);

  const int NT = K >> 5;   // 128
  for (int t = 0; t < NT; ++t) {
    const int cb_ = t & 1, nb_ = cb_ ^ 1;

    asm volatile("s_waitcnt vmcnt(0)" ::: "memory");
    __builtin_amdgcn_s_barrier();
    asm volatile("" ::: "memory");   // pin: stages stay below the barrier
    if (t + 1 < NT) stage(nb_, t + 1);

    u32x4 bf[NIF];
#pragma unroll
    for (int ni = 0; ni < NIF; ++ni) bf[ni] = rdB(cb_, ni);
    __builtin_amdgcn_s_setprio(1);
#pragma unroll
    for (int mi = 0; mi < 8; ++mi) {
      u32x4 a = rdA(cb_, mi);
#pragma unroll
      for (int ni = 0; ni < NIF; ++ni)
        acc[mi][ni] = MFMA16(BC8(a), BC8(bf[ni]), acc[mi][ni]);
    }
    __builtin_amdgcn_s_setprio(0);
  }

  const int crow0 = m0 + wr * 128;
  const int ccol0 = n0 + wc * (NIF * 16);
#pragma unroll
  for (int mi = 0; mi < 8; ++mi)
#pragma unroll
    for (int ni = 0; ni < NIF; ++ni)
#pragma unroll
      for (int r = 0; r < 4; ++r) {
        const size_t idx =
            (size_t)(crow0 + mi * 16 + g * 4 + r) * N + (ccol0 + ni * 16 + l15);
        if constexpr (OUTF32) ((float*)Cout)[idx] = acc[mi][ni][r];
        else ((unsigned short*)Cout)[idx] = f2bf(acc[mi][ni][r]);
      }
}

// ---------------------------------------------------------------------------
// Flash attention, GQA, causal + sliding window 1024, fused Q-RoPE.
// (unchanged from the 475-us builds)
// ---------------------------------------------------------------------------
__global__ __launch_bounds__(512, 2) void attn_kernel(const unsigned short* __restrict__ qkv,
                                                      unsigned short* __restrict__ aout,
                                                      const int* __restrict__ pos) {
  __shared__ __align__(16) unsigned short smem[35840];   // 2 buffers, 70 KiB

  const int tid = threadIdx.x;
  const int lane = tid & 63;
  const int w = tid >> 6;
  const int hi = lane >> 5;
  const int l31 = lane & 31;
  const int q0 = blockIdx.x * 256;
  const int h = blockIdx.y;
  const int b = blockIdx.z;
  const int kh = h >> 2;
  const size_t tokbase = (size_t)b * 2048;
  const int qw0 = q0 + w * 32;
  const int qg = qw0 + l31;

  short8 qf[8];
  {
    const unsigned short* qp = qkv + (tokbase + qg) * 6144 + h * 128;
#pragma unroll
    for (int ks8 = 0; ks8 < 8; ++ks8)
      qf[ks8] = BC8(*(const u32x4*)(qp + ks8 * 16 + hi * 8));
    const float fp = (float)pos[qg];
#pragma unroll
    for (int ks8 = 0; ks8 < 4; ++ks8)
#pragma unroll
      for (int j = 0; j < 8; ++j) {
        const int d = ks8 * 16 + hi * 8 + j;
        const float x1 = bf2f((unsigned short)qf[ks8][j]);
        const float x2 = bf2f((unsigned short)qf[ks8 + 4][j]);
        const float ang = fp * exp2f(-(float)d * 0.2076205059304601f);
        float c, sn;
        __sincosf(ang, &sn, &c);
        qf[ks8][j]     = (short)f2bf(x1 * c - x2 * sn);
        qf[ks8 + 4][j] = (short)f2bf(x2 * c + x1 * sn);
      }
  }

  const int c0key = tid >> 4, c0col = tid & 15;
  const int c1key = (tid + 512) >> 4, c1col = tid & 15;

  u32x4 kreg[2], vreg[2];
  const unsigned short* kvK = qkv + tokbase * 6144 + 4096 + kh * 128;

  const int t0 = (q0 >= 1024 ? (q0 - 1023) >> 6 : 0);
  const int t1 = (q0 + 255) >> 6;

  {
    const unsigned short* kb = kvK + (size_t)(t0 * 64) * 6144;
    kreg[0] = *(const u32x4*)(kb + (size_t)c0key * 6144 + c0col * 8);
    kreg[1] = *(const u32x4*)(kb + (size_t)c1key * 6144 + c1col * 8);
    vreg[0] = *(const u32x4*)(kb + (size_t)c0key * 6144 + 1024 + c0col * 8);
    vreg[1] = *(const u32x4*)(kb + (size_t)c1key * 6144 + 1024 + c1col * 8);
  }

  float m_run = -1e30f, l_run = 0.0f;
  f32x16 o_acc[4] = {};

  for (int kt = t0; kt <= t1; ++kt) {
    const int cur = (kt - t0) & 1;
    unsigned short* kdst = &smem[(cur)*17920];
    unsigned short* vdst = kdst + 8704;

    if (kt == t0) {
      *(u32x4*)&kdst[c0key * 136 + c0col * 8] = kreg[0];
      *(u32x4*)&kdst[c1key * 136 + c1col * 8] = kreg[1];
#pragma unroll
      for (int e = 0; e < 8; ++e) {
        const int e0 = (e + c0col) & 7;
        const int e1 = (e + c1col) & 7;
        vdst[(c0col * 8 + e0) * 72 + c0key] =
            (unsigned short)(vreg[0][e0 >> 1] >> ((e0 & 1) * 16));
        vdst[(c1col * 8 + e1) * 72 + c1key] =
            (unsigned short)(vreg[1][e1 >> 1] >> ((e1 & 1) * 16));
      }
      if (kt < t1) {
        const unsigned short* kb = kvK + (size_t)((kt + 1) * 64) * 6144;
        kreg[0] = *(const u32x4*)(kb + (size_t)c0key * 6144 + c0col * 8);
        kreg[1] = *(const u32x4*)(kb + (size_t)c1key * 6144 + c1col * 8);
        vreg[0] = *(const u32x4*)(kb + (size_t)c0key * 6144 + 1024 + c0col * 8);
        vreg[1] = *(const u32x4*)(kb + (size_t)c1key * 6144 + 1024 + c1col * 8);
      }
      __syncthreads();
    }

    if (kt < t1) {
      unsigned short* kdn = &smem[(cur ^ 1) * 17920];
      unsigned short* vdn = kdn + 8704;
      *(u32x4*)&kdn[c0key * 136 + c0col * 8] = kreg[0];
      *(u32x4*)&kdn[c1key * 136 + c1col * 8] = kreg[1];
#pragma unroll
      for (int e = 0; e < 8; ++e) {
        const int e0 = (e + c0col) & 7;
        const int e1 = (e + c1col) & 7;
        vdn[(c0col * 8 + e0) * 72 + c0key] =
            (unsigned short)(vreg[0][e0 >> 1] >> ((e0 & 1) * 16));
        vdn[(c1col * 8 + e1) * 72 + c1key] =
            (unsigned short)(vreg[1][e1 >> 1] >> ((e1 & 1) * 16));
      }
      if (kt + 2 <= t1) {
        const unsigned short* kb = kvK + (size_t)((kt + 2) * 64) * 6144;
        kreg[0] = *(const u32x4*)(kb + (size_t)c0key * 6144 + c0col * 8);
        kreg[1] = *(const u32x4*)(kb + (size_t)c1key * 6144 + c1col * 8);
        vreg[0] = *(const u32x4*)(kb + (size_t)c0key * 6144 + 1024 + c0col * 8);
        vreg[1] = *(const u32x4*)(kb + (size_t)c1key * 6144 + 1024 + c1col * 8);
      }
    }

    const int ktb = kt * 64;
    if (ktb <= qw0 + 31 && ktb + 63 >= qw0 - 1023) {
      const unsigned short* kb = &smem[cur * 17920];
      const unsigned short* vb = kb + 8704;

      f32x16 s0 = {}, s1 = {};
      const int arow = l31 * 136 + hi * 8;
#pragma unroll
      for (int ks8 = 0; ks8 < 8; ++ks8) {
        u32x4 a0 = *(const u32x4*)&kb[arow + ks8 * 16];
        u32x4 a1 = *(const u32x4*)&kb[arow + 32 * 136 + ks8 * 16];
        s0 = MFMA32(BC8(a0), qf[ks8], s0);
        s1 = MFMA32(BC8(a1), qf[ks8], s1);
      }

      const float scale = 0.08838834764831845f;
      float pv[32];
      const bool need_mask = !(ktb + 63 <= qw0 && ktb >= qw0 - 992);
      if (need_mask) {
#pragma unroll
        for (int r = 0; r < 16; ++r) {
          const int key0 = ktb + ((r & 3) + 8 * (r >> 2) + 4 * hi);
          const int key1 = key0 + 32;
          pv[r]      = (key0 <= qg && qg - key0 < 1024) ? s0[r] * scale : -1e30f;
          pv[16 + r] = (key1 <= qg && qg - key1 < 1024) ? s1[r] * scale : -1e30f;
        }
      } else {
#pragma unroll
        for (int r = 0; r < 16; ++r) {
          pv[r] = s0[r] * scale;
          pv[16 + r] = s1[r] * scale;
        }
      }

      float tm = -1e30f;
#pragma unroll
      for (int i = 0; i < 32; ++i) tm = fmaxf(tm, pv[i]);
      tm = fmaxf(tm, __shfl_xor(tm, 32, 64));
      if (__any(tm > m_run + 8.0f)) {
        const float mn = fmaxf(fmaxf(m_run, tm), -1e20f);
        const float scl = __expf(m_run - mn);
#pragma unroll
        for (int d = 0; d < 4; ++d) o_acc[d] *= scl;
        l_run *= scl;
        m_run = mn;
      }
      float lsum = 0.0f;
#pragma unroll
      for (int i = 0; i < 32; ++i) {
        pv[i] = __expf(pv[i] - m_run);
        lsum += pv[i];
      }
      l_run += lsum + __shfl_xor(lsum, 32, 64);

      u32x4 paf[4];
#pragma unroll
      for (int ks = 0; ks < 4; ++ks) {
        const int base = (ks >> 1) * 16 + (ks & 1) * 8;
        auto rA = __builtin_amdgcn_permlane32_swap(
            (int)cvtpk_bf16(pv[base + 0], pv[base + 1]),
            (int)cvtpk_bf16(pv[base + 4], pv[base + 5]), false, false);
        auto rB = __builtin_amdgcn_permlane32_swap(
            (int)cvtpk_bf16(pv[base + 2], pv[base + 3]),
            (int)cvtpk_bf16(pv[base + 6], pv[base + 7]), false, false);
        paf[ks][0] = (unsigned int)rA[0];
        paf[ks][1] = (unsigned int)rB[0];
        paf[ks][2] = (unsigned int)rA[1];
        paf[ks][3] = (unsigned int)rB[1];
      }

#pragma unroll
      for (int dblk = 0; dblk < 4; ++dblk) {
        const int vrow = (dblk * 32 + l31) * 72 + hi * 8;
#pragma unroll
        for (int ks = 0; ks < 4; ++ks) {
          u32x4 vf = *(const u32x4*)&vb[vrow + ks * 16];
          o_acc[dblk] = MFMA32(BC8(vf), BC8(paf[ks]), o_acc[dblk]);
        }
      }
    }

    __syncthreads();
  }

  const float rl = 1.0f / l_run;
  unsigned short* ob = &smem[w * 4352];
#pragma unroll
  for (int dblk = 0; dblk < 4; ++dblk)
#pragma unroll
    for (int rq = 0; rq < 4; ++rq) {
      u16x4 pk;
#pragma unroll
      for (int i = 0; i < 4; ++i) pk[i] = f2bf(o_acc[dblk][rq * 4 + i] * rl);
      *(u16x4*)&ob[l31 * 136 + dblk * 32 + rq * 8 + hi * 4] = pk;
    }
  __syncthreads();

  unsigned short* gout = aout + (tokbase + q0 + w * 32) * 4096 + h * 128;
#pragma unroll
  for (int r4 = 0; r4 < 8; ++r4) {
    const int row = r4 * 4 + (lane >> 4);
    u32x4 val = *(const u32x4*)&ob[row * 136 + (lane & 15) * 8];
    *(u32x4*)(gout + (size_t)row * 4096 + (lane & 15) * 8) = val;
  }
}

// ---------------------------------------------------------------------------
// launch
// ---------------------------------------------------------------------------
extern "C" void kernel_launch(void* const* d_in, const int* in_sizes, int n_in,
                              void* d_out, int out_size, void* d_ws, size_t ws_size,
                              hipStream_t stream) {
  (void)in_sizes; (void)n_in; (void)out_size; (void)ws_size;
  const float* hs   = (const float*)d_in[0];   // [2,2048,4096]
  const float* wqkv = (const float*)d_in[1];   // [4096,6144]
  const float* wo   = (const float*)d_in[2];   // [4096,4096]
  const int*   pos  = (const int*)d_in[3];     // [2048]
  float* out = (float*)d_out;                  // [2,2048,4096] fp32

  char* ws = (char*)d_ws;
  unsigned short* qkvb = (unsigned short*)ws;                // [4096][6144] bf16
  unsigned short* wT   = (unsigned short*)(ws + 50331648);   // weightT bf16
  unsigned short* hsb  = (unsigned short*)(ws + 100663296);  // [4096][4096] bf16

  cvt1<<<40960, 256, 0, stream>>>(hs, wqkv, hsb, wT);
  // GEMM1: BK=32 tile 256x192 (R12-exact, 188 us), 2 blocks/CU, grid 512
  gemm_k32<3, 0><<<512, 512, 0, stream>>>(hsb, wT, qkvb, 4096, 6144, 4096);
  rope_cvtwo<<<24576, 256, 0, stream>>>(qkvb, pos, wo, wT);
  attn_kernel<<<dim3(8, 32, 2), 512, 0, stream>>>(qkvb, hsb, pos);
  // GEMM2: BK=32 tile 256x128, 48 KB LDS -> 2-3 blocks/CU, grid 512
  gemm_k32<2, 1><<<512, 512, 0, stream>>>(hsb, wT, out, 4096, 4096, 4096);
}

// Round 15
// 482.215 us; speedup vs baseline: 1.0207x; 1.0207x over previous
//
#include <hip/hip_runtime.h>

// ---------------------------------------------------------------------------
// MixtralAttention on MI355X (gfx950)
// B=2, S=2048, HID=4096, NH=32, NKV=8, HD=128, WINDOW=1024, THETA=10000
// Final per-component-best build:
//   GEMM1: BK=32 single-sync, tile 256x192 (NIF=3), grid 512, 2 blocks/CU
//          [186.5 us measured; overhead-bound structure, best at this grid]
//   GEMM2: 8-phase NIF4 256x256, grid 256 = 1.0 CU-wave [~106 us, 1296 TF]
//   attn : 8-wave swapped-QKT/PV flash, fused Q-RoPE [<100 us]
// NOTE: SQ_LDS_BANK_CONFLICT ~2.3e7 in gemm_k32 is the inherent 1024B
// gload_lds write serialization (R13 arithmetic match) - not actionable.
// ---------------------------------------------------------------------------

typedef __attribute__((ext_vector_type(8))) short short8;       // bf16x8 frag
typedef __attribute__((ext_vector_type(4))) float f32x4;        // 16x16 acc
typedef __attribute__((ext_vector_type(16))) float f32x16;      // 32x32 acc
typedef __attribute__((ext_vector_type(4))) unsigned int u32x4; // 16B load
typedef __attribute__((ext_vector_type(4))) unsigned short u16x4;

__device__ __forceinline__ unsigned short f2bf(float f) {
  unsigned int u = __builtin_bit_cast(unsigned int, f);
  u = u + 0x7fffu + ((u >> 16) & 1u);   // round-to-nearest-even
  return (unsigned short)(u >> 16);
}
__device__ __forceinline__ float bf2f(unsigned short h) {
  unsigned int u = ((unsigned int)h) << 16;
  return __builtin_bit_cast(float, u);
}
__device__ __forceinline__ unsigned int cvtpk_bf16(float lo, float hi) {
  unsigned int r;
  asm("v_cvt_pk_bf16_f32 %0, %1, %2" : "=v"(r) : "v"(lo), "v"(hi));
  return r;
}

__device__ __forceinline__ void gload_lds16(const unsigned short* g, unsigned short* l) {
  __builtin_amdgcn_global_load_lds(
      (const __attribute__((address_space(1))) unsigned int*)g,
      (__attribute__((address_space(3))) unsigned int*)l, 16, 0, 0);
}

#define MFMA16(A, B, C) __builtin_amdgcn_mfma_f32_16x16x32_bf16((A), (B), (C), 0, 0, 0)
#define MFMA32(A, B, C) __builtin_amdgcn_mfma_f32_32x32x16_bf16((A), (B), (C), 0, 0, 0)
#define BC8(x) __builtin_bit_cast(short8, (x))

// ---------------------------------------------------------------------------
// merged: cvt_t(wqkv -> wqkvT) + cvt_plain(hs -> hsb)
// ---------------------------------------------------------------------------
__global__ __launch_bounds__(256) void cvt1(const float* __restrict__ hs,
                                            const float* __restrict__ wqkv,
                                            unsigned short* __restrict__ hsb,
                                            unsigned short* __restrict__ wT) {
  const int bid = blockIdx.x;
  if (bid < 24576) {
    __shared__ float t[32][33];
    const int c0 = (bid % 192) * 32, r0 = (bid / 192) * 32;  // R=4096, C=6144
    const int tx = threadIdx.x & 31, ty = threadIdx.x >> 5;
#pragma unroll
    for (int i = 0; i < 4; ++i)
      t[ty + i * 8][tx] = wqkv[(size_t)(r0 + ty + i * 8) * 6144 + c0 + tx];
    __syncthreads();
#pragma unroll
    for (int i = 0; i < 4; ++i)
      wT[(size_t)(c0 + ty + i * 8) * 4096 + r0 + tx] = f2bf(t[tx][ty + i * 8]);
  } else {
    const int i = ((bid - 24576) * 256 + threadIdx.x) * 4;
    f32x4 v = *(const f32x4*)(hs + i);
    u16x4 o;
#pragma unroll
    for (int j = 0; j < 4; ++j) o[j] = f2bf(v[j]);
    *(u16x4*)(hsb + i) = o;
  }
}

// ---------------------------------------------------------------------------
// merged: rope_k (K heads in qkv) + cvt_t(wo -> woT)
// ---------------------------------------------------------------------------
__global__ __launch_bounds__(256) void rope_cvtwo(unsigned short* __restrict__ qkv,
                                                  const int* __restrict__ pos,
                                                  const float* __restrict__ wo,
                                                  unsigned short* __restrict__ wT) {
  const int bid = blockIdx.x;
  if (bid < 8192) {
    const int idx = bid * 256 + threadIdx.x;   // < 4096*8*64
    const int d = idx & 63;
    const int hh = (idx >> 6) & 7;
    const int tok = idx >> 9;
    const int s = tok & 2047;
    unsigned short* p = qkv + (size_t)tok * 6144 + 4096 + hh * 128 + d;
    const float x1 = bf2f(p[0]);
    const float x2 = bf2f(p[64]);
    const float inv = exp2f(-(float)d * 0.2076205059304601f);
    const float ang = (float)pos[s] * inv;
    const float c = cosf(ang), sn = sinf(ang);
    p[0]  = f2bf(x1 * c - x2 * sn);
    p[64] = f2bf(x2 * c + x1 * sn);
  } else {
    __shared__ float t[32][33];
    const int b2 = bid - 8192;
    const int c0 = (b2 % 128) * 32, r0 = (b2 / 128) * 32;   // R=C=4096
    const int tx = threadIdx.x & 31, ty = threadIdx.x >> 5;
#pragma unroll
    for (int i = 0; i < 4; ++i)
      t[ty + i * 8][tx] = wo[(size_t)(r0 + ty + i * 8) * 4096 + c0 + tx];
    __syncthreads();
#pragma unroll
    for (int i = 0; i < 4; ++i)
      wT[(size_t)(c0 + ty + i * 8) * 4096 + r0 + tx] = f2bf(t[tx][ty + i * 8]);
  }
}

// ---------------------------------------------------------------------------
// GEMM1: C[M,N] = A[M,K] * B^T[N,K], tile 256x192 (NIF=3), BK=32, grid 512.
// LDS 2 x 28 KB -> 2 blocks/CU; cross-block overlap hides the vmcnt(0).
// Per K-tile: { vmcnt(0); s_barrier; stage(t+1); 24 MFMA }. (R12/R14-exact)
// ---------------------------------------------------------------------------
__global__ __launch_bounds__(512, 4) void gemm_k32(const unsigned short* __restrict__ A,
                                                   const unsigned short* __restrict__ BT,
                                                   unsigned short* __restrict__ Cout,
                                                   int M, int N, int K) {
  __shared__ __align__(16) unsigned short lds[2][14336];   // 2 x 28 KB
  const int tid = threadIdx.x;
  const int lane = tid & 63;
  const int w = tid >> 6;          // wave 0..7
  const int wr = w >> 2;           // 0..1 (M)
  const int wc = w & 3;            // 0..3 (N)
  const int g = lane >> 4;
  const int l15 = lane & 15;

  const int nwg = gridDim.x;
  const int cpx = nwg >> 3;
  const int bid = blockIdx.x;
  const int swz = (bid & 7) * cpx + (bid >> 3);
  const int MT = M >> 8;
  const int m0 = (swz % MT) * 256;
  const int n0 = (swz / MT) * 192;

  const int lr = lane >> 2;          // 0..15
  const int lq = (lane & 3) * 8;     // 0,8,16,24 (elems)
  const unsigned short* Asrc = A + (size_t)(m0 + lr) * K + lq;
  const unsigned short* Bsrc = BT + (size_t)(n0 + lr) * K + lq;

  f32x4 acc[8][3] = {};

  auto stage = [&](int buf, int t) {
    const int tc = t * 32;
    gload_lds16(Asrc + (size_t)(w * 16) * K + tc, &lds[buf][w * 512]);
    gload_lds16(Asrc + (size_t)(128 + w * 16) * K + tc, &lds[buf][4096 + w * 512]);
    gload_lds16(Bsrc + (size_t)(w * 16) * K + tc, &lds[buf][8192 + w * 512]);
    if (w < 4)
      gload_lds16(Bsrc + (size_t)(128 + w * 16) * K + tc, &lds[buf][12288 + w * 512]);
  };
  auto rdA = [&](int buf, int mi) {
    const int row = wr * 128 + mi * 16 + l15;
    return *(const u32x4*)&lds[buf][row * 32 + g * 8];
  };
  auto rdB = [&](int buf, int ni) {
    const int row = wc * 48 + ni * 16 + l15;
    return *(const u32x4*)&lds[buf][8192 + row * 32 + g * 8];
  };

  stage(0, 0);

  const int NT = K >> 5;   // 128
  for (int t = 0; t < NT; ++t) {
    const int cb_ = t & 1, nb_ = cb_ ^ 1;

    asm volatile("s_waitcnt vmcnt(0)" ::: "memory");
    __builtin_amdgcn_s_barrier();
    asm volatile("" ::: "memory");   // pin: stages stay below the barrier
    if (t + 1 < NT) stage(nb_, t + 1);

    u32x4 b0 = rdB(cb_, 0), b1 = rdB(cb_, 1), b2 = rdB(cb_, 2);
    __builtin_amdgcn_s_setprio(1);
#pragma unroll
    for (int mi = 0; mi < 8; ++mi) {
      u32x4 a = rdA(cb_, mi);
      acc[mi][0] = MFMA16(BC8(a), BC8(b0), acc[mi][0]);
      acc[mi][1] = MFMA16(BC8(a), BC8(b1), acc[mi][1]);
      acc[mi][2] = MFMA16(BC8(a), BC8(b2), acc[mi][2]);
    }
    __builtin_amdgcn_s_setprio(0);
  }

  const int crow0 = m0 + wr * 128;
  const int ccol0 = n0 + wc * 48;
#pragma unroll
  for (int mi = 0; mi < 8; ++mi)
#pragma unroll
    for (int ni = 0; ni < 3; ++ni)
#pragma unroll
      for (int r = 0; r < 4; ++r) {
        const size_t idx =
            (size_t)(crow0 + mi * 16 + g * 4 + r) * N + (ccol0 + ni * 16 + l15);
        Cout[idx] = f2bf(acc[mi][ni][r]);
      }
}

// ---------------------------------------------------------------------------
// GEMM2: 8-phase template, NIF=4 256x256, grid 256 = 1.0 CU-wave (~1296 TF).
// ---------------------------------------------------------------------------
template <int NIF, int OUTF32>
__global__ __launch_bounds__(512, 2) void gemm_p4(const unsigned short* __restrict__ A,
                                                  const unsigned short* __restrict__ BT,
                                                  void* __restrict__ Cout,
                                                  int M, int N, int K) {
  constexpr int BUFE = 16384 + NIF * 4096;
  constexpr int NR = NIF + 4;
  __shared__ __align__(16) unsigned short lds[2][BUFE];
  const int tid = threadIdx.x;
  const int lane = tid & 63;
  const int w = tid >> 6;
  const int wr = w >> 2;
  const int wc = w & 3;
  const int g = lane >> 4;
  const int l15 = lane & 15;

  const int nwg = gridDim.x;
  const int cpx = nwg >> 3;
  const int bid = blockIdx.x;
  const int swz = (bid & 7) * cpx + (bid >> 3);
  const int MT = M >> 8;
  const int m0 = (swz % MT) * 256;
  const int n0 = (swz / MT) * (NIF * 64);

  const int lrow = lane >> 3;
  const int lcol = ((lane & 7) ^ lrow) * 8;
  const unsigned short* Asrc = A + (size_t)(m0 + w * 8 + lrow) * K + lcol;
  const unsigned short* Bsrc = BT + (size_t)(n0 + w * 8 + lrow) * K + lcol;

  f32x4 acc[8][NIF] = {};

  auto stage = [&](int buf, int t, int r) {
    if (r < NIF) {
      const int rb = r * 64;
      gload_lds16(Bsrc + (size_t)rb * K + t * 64,
                  &lds[buf][16384 + (rb + w * 8) * 64]);
    } else {
      const int j = r - NIF;
      const int rb = (j & 1) * 128 + ((j >> 1) & 1) * 64;
      gload_lds16(Asrc + (size_t)rb * K + t * 64,
                  &lds[buf][(rb + w * 8) * 64]);
    }
  };
  auto rdA = [&](int buf, int mi, int ks) {
    const int row = wr * 128 + mi * 16 + l15;
    const int cb = (ks * 64 + g * 16) ^ ((l15 & 7) << 4);
    return *(const u32x4*)((const char*)&lds[buf][0] + row * 128 + cb);
  };
  auto rdB = [&](int buf, int ni, int ks) {
    const int row = wc * (NIF * 16) + ni * 16 + l15;
    const int cb = (ks * 64 + g * 16) ^ ((l15 & 7) << 4);
    return *(const u32x4*)((const char*)&lds[buf][0] + 32768 + row * 128 + cb);
  };

#pragma unroll
  for (int r = 0; r < NR; ++r) stage(0, 0, r);
  asm volatile("s_waitcnt vmcnt(2)" ::: "memory");
  __builtin_amdgcn_sched_barrier(0);
  __builtin_amdgcn_s_barrier();

  const int NT = K >> 6;
  for (int t = 0; t < NT; ++t) {
    const int cb_ = t & 1, nb_ = cb_ ^ 1;
    const bool pre = (t + 1 < NT);
    u32x4 bfr[NIF][2];

    // ---------------- P0 : mi 0,1 (+ all B frags) ----------------
    {
#pragma unroll
      for (int ni = 0; ni < NIF; ++ni) {
        bfr[ni][0] = rdB(cb_, ni, 0);
        bfr[ni][1] = rdB(cb_, ni, 1);
      }
      u32x4 a00 = rdA(cb_, 0, 0), a01 = rdA(cb_, 0, 1);
      u32x4 a10 = rdA(cb_, 1, 0), a11 = rdA(cb_, 1, 1);
      if (pre) { stage(nb_, t + 1, 0); stage(nb_, t + 1, 1); }
      __builtin_amdgcn_sched_barrier(0);
      __builtin_amdgcn_s_barrier();
      asm volatile("s_waitcnt lgkmcnt(0)" ::: "memory");
      __builtin_amdgcn_sched_barrier(0);
      __builtin_amdgcn_s_setprio(1);
#pragma unroll
      for (int ni = 0; ni < NIF; ++ni) {
        acc[0][ni] = MFMA16(BC8(a00), BC8(bfr[ni][0]), acc[0][ni]);
        acc[0][ni] = MFMA16(BC8(a01), BC8(bfr[ni][1]), acc[0][ni]);
        acc[1][ni] = MFMA16(BC8(a10), BC8(bfr[ni][0]), acc[1][ni]);
        acc[1][ni] = MFMA16(BC8(a11), BC8(bfr[ni][1]), acc[1][ni]);
      }
      __builtin_amdgcn_s_setprio(0);
      __builtin_amdgcn_sched_barrier(0);
      __builtin_amdgcn_s_barrier();
    }
    // ---------------- P1 : mi 2,3 ----------------
    {
      u32x4 a00 = rdA(cb_, 2, 0), a01 = rdA(cb_, 2, 1);
      u32x4 a10 = rdA(cb_, 3, 0), a11 = rdA(cb_, 3, 1);
      if (pre) {
        stage(nb_, t + 1, 2); stage(nb_, t + 1, 3);
        asm volatile("s_waitcnt vmcnt(4)" ::: "memory");
      } else {
        asm volatile("s_waitcnt vmcnt(0)" ::: "memory");
      }
      __builtin_amdgcn_sched_barrier(0);
      __builtin_amdgcn_s_barrier();
      asm volatile("s_waitcnt lgkmcnt(0)" ::: "memory");
      __builtin_amdgcn_sched_barrier(0);
      __builtin_amdgcn_s_setprio(1);
#pragma unroll
      for (int ni = 0; ni < NIF; ++ni) {
        acc[2][ni] = MFMA16(BC8(a00), BC8(bfr[ni][0]), acc[2][ni]);
        acc[2][ni] = MFMA16(BC8(a01), BC8(bfr[ni][1]), acc[2][ni]);
        acc[3][ni] = MFMA16(BC8(a10), BC8(bfr[ni][0]), acc[3][ni]);
        acc[3][ni] = MFMA16(BC8(a11), BC8(bfr[ni][1]), acc[3][ni]);
      }
      __builtin_amdgcn_s_setprio(0);
      __builtin_amdgcn_sched_barrier(0);
      __builtin_amdgcn_s_barrier();
    }
    // ---------------- P2 : mi 4,5 ----------------
    {
      u32x4 a00 = rdA(cb_, 4, 0), a01 = rdA(cb_, 4, 1);
      u32x4 a10 = rdA(cb_, 5, 0), a11 = rdA(cb_, 5, 1);
      if (pre) { stage(nb_, t + 1, 4); stage(nb_, t + 1, 5); }
      __builtin_amdgcn_sched_barrier(0);
      __builtin_amdgcn_s_barrier();
      asm volatile("s_waitcnt lgkmcnt(0)" ::: "memory");
      __builtin_amdgcn_sched_barrier(0);
      __builtin_amdgcn_s_setprio(1);
#pragma unroll
      for (int ni = 0; ni < NIF; ++ni) {
        acc[4][ni] = MFMA16(BC8(a00), BC8(bfr[ni][0]), acc[4][ni]);
        acc[4][ni] = MFMA16(BC8(a01), BC8(bfr[ni][1]), acc[4][ni]);
        acc[5][ni] = MFMA16(BC8(a10), BC8(bfr[ni][0]), acc[5][ni]);
        acc[5][ni] = MFMA16(BC8(a11), BC8(bfr[ni][1]), acc[5][ni]);
      }
      __builtin_amdgcn_s_setprio(0);
      __builtin_amdgcn_sched_barrier(0);
      __builtin_amdgcn_s_barrier();
    }
    // ---------------- P3 : mi 6,7 ----------------
    {
      u32x4 a00 = rdA(cb_, 6, 0), a01 = rdA(cb_, 6, 1);
      u32x4 a10 = rdA(cb_, 7, 0), a11 = rdA(cb_, 7, 1);
      if (pre) {
        stage(nb_, t + 1, 6);
        if (NR == 8) stage(nb_, t + 1, 7);
        asm volatile("s_waitcnt vmcnt(2)" ::: "memory");
      }
      __builtin_amdgcn_sched_barrier(0);
      __builtin_amdgcn_s_barrier();
      asm volatile("s_waitcnt lgkmcnt(0)" ::: "memory");
      __builtin_amdgcn_sched_barrier(0);
      __builtin_amdgcn_s_setprio(1);
#pragma unroll
      for (int ni = 0; ni < NIF; ++ni) {
        acc[6][ni] = MFMA16(BC8(a00), BC8(bfr[ni][0]), acc[6][ni]);
        acc[6][ni] = MFMA16(BC8(a01), BC8(bfr[ni][1]), acc[6][ni]);
        acc[7][ni] = MFMA16(BC8(a10), BC8(bfr[ni][0]), acc[7][ni]);
        acc[7][ni] = MFMA16(BC8(a11), BC8(bfr[ni][1]), acc[7][ni]);
      }
      __builtin_amdgcn_s_setprio(0);
      __builtin_amdgcn_sched_barrier(0);
      __builtin_amdgcn_s_barrier();
    }
  }

  const int crow0 = m0 + wr * 128;
  const int ccol0 = n0 + wc * (NIF * 16);
#pragma unroll
  for (int mi = 0; mi < 8; ++mi)
#pragma unroll
    for (int ni = 0; ni < NIF; ++ni)
#pragma unroll
      for (int r = 0; r < 4; ++r) {
        const size_t idx =
            (size_t)(crow0 + mi * 16 + g * 4 + r) * N + (ccol0 + ni * 16 + l15);
        if constexpr (OUTF32) ((float*)Cout)[idx] = acc[mi][ni][r];
        else ((unsigned short*)Cout)[idx] = f2bf(acc[mi][ni][r]);
      }
}

// ---------------------------------------------------------------------------
// Flash attention, GQA, causal + sliding window 1024, fused Q-RoPE.
// ---------------------------------------------------------------------------
__global__ __launch_bounds__(512, 2) void attn_kernel(const unsigned short* __restrict__ qkv,
                                                      unsigned short* __restrict__ aout,
                                                      const int* __restrict__ pos) {
  __shared__ __align__(16) unsigned short smem[35840];   // 2 buffers, 70 KiB

  const int tid = threadIdx.x;
  const int lane = tid & 63;
  const int w = tid >> 6;
  const int hi = lane >> 5;
  const int l31 = lane & 31;
  const int q0 = blockIdx.x * 256;
  const int h = blockIdx.y;
  const int b = blockIdx.z;
  const int kh = h >> 2;
  const size_t tokbase = (size_t)b * 2048;
  const int qw0 = q0 + w * 32;
  const int qg = qw0 + l31;

  short8 qf[8];
  {
    const unsigned short* qp = qkv + (tokbase + qg) * 6144 + h * 128;
#pragma unroll
    for (int ks8 = 0; ks8 < 8; ++ks8)
      qf[ks8] = BC8(*(const u32x4*)(qp + ks8 * 16 + hi * 8));
    const float fp = (float)pos[qg];
#pragma unroll
    for (int ks8 = 0; ks8 < 4; ++ks8)
#pragma unroll
      for (int j = 0; j < 8; ++j) {
        const int d = ks8 * 16 + hi * 8 + j;
        const float x1 = bf2f((unsigned short)qf[ks8][j]);
        const float x2 = bf2f((unsigned short)qf[ks8 + 4][j]);
        const float ang = fp * exp2f(-(float)d * 0.2076205059304601f);
        float c, sn;
        __sincosf(ang, &sn, &c);
        qf[ks8][j]     = (short)f2bf(x1 * c - x2 * sn);
        qf[ks8 + 4][j] = (short)f2bf(x2 * c + x1 * sn);
      }
  }

  const int c0key = tid >> 4, c0col = tid & 15;
  const int c1key = (tid + 512) >> 4, c1col = tid & 15;

  u32x4 kreg[2], vreg[2];
  const unsigned short* kvK = qkv + tokbase * 6144 + 4096 + kh * 128;

  const int t0 = (q0 >= 1024 ? (q0 - 1023) >> 6 : 0);
  const int t1 = (q0 + 255) >> 6;

  {
    const unsigned short* kb = kvK + (size_t)(t0 * 64) * 6144;
    kreg[0] = *(const u32x4*)(kb + (size_t)c0key * 6144 + c0col * 8);
    kreg[1] = *(const u32x4*)(kb + (size_t)c1key * 6144 + c1col * 8);
    vreg[0] = *(const u32x4*)(kb + (size_t)c0key * 6144 + 1024 + c0col * 8);
    vreg[1] = *(const u32x4*)(kb + (size_t)c1key * 6144 + 1024 + c1col * 8);
  }

  float m_run = -1e30f, l_run = 0.0f;
  f32x16 o_acc[4] = {};

  for (int kt = t0; kt <= t1; ++kt) {
    const int cur = (kt - t0) & 1;
    unsigned short* kdst = &smem[(cur)*17920];
    unsigned short* vdst = kdst + 8704;

    if (kt == t0) {
      *(u32x4*)&kdst[c0key * 136 + c0col * 8] = kreg[0];
      *(u32x4*)&kdst[c1key * 136 + c1col * 8] = kreg[1];
#pragma unroll
      for (int e = 0; e < 8; ++e) {
        const int e0 = (e + c0col) & 7;
        const int e1 = (e + c1col) & 7;
        vdst[(c0col * 8 + e0) * 72 + c0key] =
            (unsigned short)(vreg[0][e0 >> 1] >> ((e0 & 1) * 16));
        vdst[(c1col * 8 + e1) * 72 + c1key] =
            (unsigned short)(vreg[1][e1 >> 1] >> ((e1 & 1) * 16));
      }
      if (kt < t1) {
        const unsigned short* kb = kvK + (size_t)((kt + 1) * 64) * 6144;
        kreg[0] = *(const u32x4*)(kb + (size_t)c0key * 6144 + c0col * 8);
        kreg[1] = *(const u32x4*)(kb + (size_t)c1key * 6144 + c1col * 8);
        vreg[0] = *(const u32x4*)(kb + (size_t)c0key * 6144 + 1024 + c0col * 8);
        vreg[1] = *(const u32x4*)(kb + (size_t)c1key * 6144 + 1024 + c1col * 8);
      }
      __syncthreads();
    }

    if (kt < t1) {
      unsigned short* kdn = &smem[(cur ^ 1) * 17920];
      unsigned short* vdn = kdn + 8704;
      *(u32x4*)&kdn[c0key * 136 + c0col * 8] = kreg[0];
      *(u32x4*)&kdn[c1key * 136 + c1col * 8] = kreg[1];
#pragma unroll
      for (int e = 0; e < 8; ++e) {
        const int e0 = (e + c0col) & 7;
        const int e1 = (e + c1col) & 7;
        vdn[(c0col * 8 + e0) * 72 + c0key] =
            (unsigned short)(vreg[0][e0 >> 1] >> ((e0 & 1) * 16));
        vdn[(c1col * 8 + e1) * 72 + c1key] =
            (unsigned short)(vreg[1][e1 >> 1] >> ((e1 & 1) * 16));
      }
      if (kt + 2 <= t1) {
        const unsigned short* kb = kvK + (size_t)((kt + 2) * 64) * 6144;
        kreg[0] = *(const u32x4*)(kb + (size_t)c0key * 6144 + c0col * 8);
        kreg[1] = *(const u32x4*)(kb + (size_t)c1key * 6144 + c1col * 8);
        vreg[0] = *(const u32x4*)(kb + (size_t)c0key * 6144 + 1024 + c0col * 8);
        vreg[1] = *(const u32x4*)(kb + (size_t)c1key * 6144 + 1024 + c1col * 8);
      }
    }

    const int ktb = kt * 64;
    if (ktb <= qw0 + 31 && ktb + 63 >= qw0 - 1023) {
      const unsigned short* kb = &smem[cur * 17920];
      const unsigned short* vb = kb + 8704;

      f32x16 s0 = {}, s1 = {};
      const int arow = l31 * 136 + hi * 8;
#pragma unroll
      for (int ks8 = 0; ks8 < 8; ++ks8) {
        u32x4 a0 = *(const u32x4*)&kb[arow + ks8 * 16];
        u32x4 a1 = *(const u32x4*)&kb[arow + 32 * 136 + ks8 * 16];
        s0 = MFMA32(BC8(a0), qf[ks8], s0);
        s1 = MFMA32(BC8(a1), qf[ks8], s1);
      }

      const float scale = 0.08838834764831845f;
      float pv[32];
      const bool need_mask = !(ktb + 63 <= qw0 && ktb >= qw0 - 992);
      if (need_mask) {
#pragma unroll
        for (int r = 0; r < 16; ++r) {
          const int key0 = ktb + ((r & 3) + 8 * (r >> 2) + 4 * hi);
          const int key1 = key0 + 32;
          pv[r]      = (key0 <= qg && qg - key0 < 1024) ? s0[r] * scale : -1e30f;
          pv[16 + r] = (key1 <= qg && qg - key1 < 1024) ? s1[r] * scale : -1e30f;
        }
      } else {
#pragma unroll
        for (int r = 0; r < 16; ++r) {
          pv[r] = s0[r] * scale;
          pv[16 + r] = s1[r] * scale;
        }
      }

      float tm = -1e30f;
#pragma unroll
      for (int i = 0; i < 32; ++i) tm = fmaxf(tm, pv[i]);
      tm = fmaxf(tm, __shfl_xor(tm, 32, 64));
      if (__any(tm > m_run + 8.0f)) {
        const float mn = fmaxf(fmaxf(m_run, tm), -1e20f);
        const float scl = __expf(m_run - mn);
#pragma unroll
        for (int d = 0; d < 4; ++d) o_acc[d] *= scl;
        l_run *= scl;
        m_run = mn;
      }
      float lsum = 0.0f;
#pragma unroll
      for (int i = 0; i < 32; ++i) {
        pv[i] = __expf(pv[i] - m_run);
        lsum += pv[i];
      }
      l_run += lsum + __shfl_xor(lsum, 32, 64);

      u32x4 paf[4];
#pragma unroll
      for (int ks = 0; ks < 4; ++ks) {
        const int base = (ks >> 1) * 16 + (ks & 1) * 8;
        auto rA = __builtin_amdgcn_permlane32_swap(
            (int)cvtpk_bf16(pv[base + 0], pv[base + 1]),
            (int)cvtpk_bf16(pv[base + 4], pv[base + 5]), false, false);
        auto rB = __builtin_amdgcn_permlane32_swap(
            (int)cvtpk_bf16(pv[base + 2], pv[base + 3]),
            (int)cvtpk_bf16(pv[base + 6], pv[base + 7]), false, false);
        paf[ks][0] = (unsigned int)rA[0];
        paf[ks][1] = (unsigned int)rB[0];
        paf[ks][2] = (unsigned int)rA[1];
        paf[ks][3] = (unsigned int)rB[1];
      }

#pragma unroll
      for (int dblk = 0; dblk < 4; ++dblk) {
        const int vrow = (dblk * 32 + l31) * 72 + hi * 8;
#pragma unroll
        for (int ks = 0; ks < 4; ++ks) {
          u32x4 vf = *(const u32x4*)&vb[vrow + ks * 16];
          o_acc[dblk] = MFMA32(BC8(vf), BC8(paf[ks]), o_acc[dblk]);
        }
      }
    }

    __syncthreads();
  }

  const float rl = 1.0f / l_run;
  unsigned short* ob = &smem[w * 4352];
#pragma unroll
  for (int dblk = 0; dblk < 4; ++dblk)
#pragma unroll
    for (int rq = 0; rq < 4; ++rq) {
      u16x4 pk;
#pragma unroll
      for (int i = 0; i < 4; ++i) pk[i] = f2bf(o_acc[dblk][rq * 4 + i] * rl);
      *(u16x4*)&ob[l31 * 136 + dblk * 32 + rq * 8 + hi * 4] = pk;
    }
  __syncthreads();

  unsigned short* gout = aout + (tokbase + q0 + w * 32) * 4096 + h * 128;
#pragma unroll
  for (int r4 = 0; r4 < 8; ++r4) {
    const int row = r4 * 4 + (lane >> 4);
    u32x4 val = *(const u32x4*)&ob[row * 136 + (lane & 15) * 8];
    *(u32x4*)(gout + (size_t)row * 4096 + (lane & 15) * 8) = val;
  }
}

// ---------------------------------------------------------------------------
// launch
// ---------------------------------------------------------------------------
extern "C" void kernel_launch(void* const* d_in, const int* in_sizes, int n_in,
                              void* d_out, int out_size, void* d_ws, size_t ws_size,
                              hipStream_t stream) {
  (void)in_sizes; (void)n_in; (void)out_size; (void)ws_size;
  const float* hs   = (const float*)d_in[0];   // [2,2048,4096]
  const float* wqkv = (const float*)d_in[1];   // [4096,6144]
  const float* wo   = (const float*)d_in[2];   // [4096,4096]
  const int*   pos  = (const int*)d_in[3];     // [2048]
  float* out = (float*)d_out;                  // [2,2048,4096] fp32

  char* ws = (char*)d_ws;
  unsigned short* qkvb = (unsigned short*)ws;                // [4096][6144] bf16
  unsigned short* wT   = (unsigned short*)(ws + 50331648);   // weightT bf16
  unsigned short* hsb  = (unsigned short*)(ws + 100663296);  // [4096][4096] bf16

  cvt1<<<40960, 256, 0, stream>>>(hs, wqkv, hsb, wT);
  // GEMM1: BK=32 tile 256x192, 2 blocks/CU, grid 512 (186.5 us measured)
  gemm_k32<<<512, 512, 0, stream>>>(hsb, wT, qkvb, 4096, 6144, 4096);
  rope_cvtwo<<<24576, 256, 0, stream>>>(qkvb, pos, wo, wT);
  attn_kernel<<<dim3(8, 32, 2), 512, 0, stream>>>(qkvb, hsb, pos);
  // GEMM2: 8-phase NIF4 256x256, grid 256 = 1.0 CU-wave (~106 us, 1296 TF)
  gemm_p4<4, 1><<<256, 512, 0, stream>>>(hsb, wT, out, 4096, 4096, 4096);
}

// Round 16
// 471.434 us; speedup vs baseline: 1.0440x; 1.0229x over previous
//
#include <hip/hip_runtime.h>

// ---------------------------------------------------------------------------
// MixtralAttention on MI355X (gfx950)
// B=2, S=2048, HID=4096, NH=32, NKV=8, HD=128, WINDOW=1024, THETA=10000
// Build = R15 per-component-best, + attention load-balance remap:
//   attn grid flattened to 512 1D; first 256 dispatches = heavy q-blocks
//   (qb 4..7, 20 KV-tiles each), second 256 = light (qb 3..0, 16..4 tiles)
//   -> each CU co-hosts one heavy + one light block (sum <= 36 tiles vs the
//   old same-qb pairing whose worst CU carried 40).
// ---------------------------------------------------------------------------

typedef __attribute__((ext_vector_type(8))) short short8;       // bf16x8 frag
typedef __attribute__((ext_vector_type(4))) float f32x4;        // 16x16 acc
typedef __attribute__((ext_vector_type(16))) float f32x16;      // 32x32 acc
typedef __attribute__((ext_vector_type(4))) unsigned int u32x4; // 16B load
typedef __attribute__((ext_vector_type(4))) unsigned short u16x4;

__device__ __forceinline__ unsigned short f2bf(float f) {
  unsigned int u = __builtin_bit_cast(unsigned int, f);
  u = u + 0x7fffu + ((u >> 16) & 1u);   // round-to-nearest-even
  return (unsigned short)(u >> 16);
}
__device__ __forceinline__ float bf2f(unsigned short h) {
  unsigned int u = ((unsigned int)h) << 16;
  return __builtin_bit_cast(float, u);
}
__device__ __forceinline__ unsigned int cvtpk_bf16(float lo, float hi) {
  unsigned int r;
  asm("v_cvt_pk_bf16_f32 %0, %1, %2" : "=v"(r) : "v"(lo), "v"(hi));
  return r;
}

__device__ __forceinline__ void gload_lds16(const unsigned short* g, unsigned short* l) {
  __builtin_amdgcn_global_load_lds(
      (const __attribute__((address_space(1))) unsigned int*)g,
      (__attribute__((address_space(3))) unsigned int*)l, 16, 0, 0);
}

#define MFMA16(A, B, C) __builtin_amdgcn_mfma_f32_16x16x32_bf16((A), (B), (C), 0, 0, 0)
#define MFMA32(A, B, C) __builtin_amdgcn_mfma_f32_32x32x16_bf16((A), (B), (C), 0, 0, 0)
#define BC8(x) __builtin_bit_cast(short8, (x))

// ---------------------------------------------------------------------------
// merged: cvt_t(wqkv -> wqkvT) + cvt_plain(hs -> hsb)
// ---------------------------------------------------------------------------
__global__ __launch_bounds__(256) void cvt1(const float* __restrict__ hs,
                                            const float* __restrict__ wqkv,
                                            unsigned short* __restrict__ hsb,
                                            unsigned short* __restrict__ wT) {
  const int bid = blockIdx.x;
  if (bid < 24576) {
    __shared__ float t[32][33];
    const int c0 = (bid % 192) * 32, r0 = (bid / 192) * 32;  // R=4096, C=6144
    const int tx = threadIdx.x & 31, ty = threadIdx.x >> 5;
#pragma unroll
    for (int i = 0; i < 4; ++i)
      t[ty + i * 8][tx] = wqkv[(size_t)(r0 + ty + i * 8) * 6144 + c0 + tx];
    __syncthreads();
#pragma unroll
    for (int i = 0; i < 4; ++i)
      wT[(size_t)(c0 + ty + i * 8) * 4096 + r0 + tx] = f2bf(t[tx][ty + i * 8]);
  } else {
    const int i = ((bid - 24576) * 256 + threadIdx.x) * 4;
    f32x4 v = *(const f32x4*)(hs + i);
    u16x4 o;
#pragma unroll
    for (int j = 0; j < 4; ++j) o[j] = f2bf(v[j]);
    *(u16x4*)(hsb + i) = o;
  }
}

// ---------------------------------------------------------------------------
// merged: rope_k (K heads in qkv) + cvt_t(wo -> woT)
// ---------------------------------------------------------------------------
__global__ __launch_bounds__(256) void rope_cvtwo(unsigned short* __restrict__ qkv,
                                                  const int* __restrict__ pos,
                                                  const float* __restrict__ wo,
                                                  unsigned short* __restrict__ wT) {
  const int bid = blockIdx.x;
  if (bid < 8192) {
    const int idx = bid * 256 + threadIdx.x;   // < 4096*8*64
    const int d = idx & 63;
    const int hh = (idx >> 6) & 7;
    const int tok = idx >> 9;
    const int s = tok & 2047;
    unsigned short* p = qkv + (size_t)tok * 6144 + 4096 + hh * 128 + d;
    const float x1 = bf2f(p[0]);
    const float x2 = bf2f(p[64]);
    const float inv = exp2f(-(float)d * 0.2076205059304601f);
    const float ang = (float)pos[s] * inv;
    const float c = cosf(ang), sn = sinf(ang);
    p[0]  = f2bf(x1 * c - x2 * sn);
    p[64] = f2bf(x2 * c + x1 * sn);
  } else {
    __shared__ float t[32][33];
    const int b2 = bid - 8192;
    const int c0 = (b2 % 128) * 32, r0 = (b2 / 128) * 32;   // R=C=4096
    const int tx = threadIdx.x & 31, ty = threadIdx.x >> 5;
#pragma unroll
    for (int i = 0; i < 4; ++i)
      t[ty + i * 8][tx] = wo[(size_t)(r0 + ty + i * 8) * 4096 + c0 + tx];
    __syncthreads();
#pragma unroll
    for (int i = 0; i < 4; ++i)
      wT[(size_t)(c0 + ty + i * 8) * 4096 + r0 + tx] = f2bf(t[tx][ty + i * 8]);
  }
}

// ---------------------------------------------------------------------------
// GEMM1: C[M,N] = A[M,K] * B^T[N,K], tile 256x192 (NIF=3), BK=32, grid 512.
// LDS 2 x 28 KB -> 2 blocks/CU; cross-block overlap hides the vmcnt(0).
// Per K-tile: { vmcnt(0); s_barrier; stage(t+1); 24 MFMA }. (R12/R14-exact)
// ---------------------------------------------------------------------------
__global__ __launch_bounds__(512, 4) void gemm_k32(const unsigned short* __restrict__ A,
                                                   const unsigned short* __restrict__ BT,
                                                   unsigned short* __restrict__ Cout,
                                                   int M, int N, int K) {
  __shared__ __align__(16) unsigned short lds[2][14336];   // 2 x 28 KB
  const int tid = threadIdx.x;
  const int lane = tid & 63;
  const int w = tid >> 6;          // wave 0..7
  const int wr = w >> 2;           // 0..1 (M)
  const int wc = w & 3;            // 0..3 (N)
  const int g = lane >> 4;
  const int l15 = lane & 15;

  const int nwg = gridDim.x;
  const int cpx = nwg >> 3;
  const int bid = blockIdx.x;
  const int swz = (bid & 7) * cpx + (bid >> 3);
  const int MT = M >> 8;
  const int m0 = (swz % MT) * 256;
  const int n0 = (swz / MT) * 192;

  const int lr = lane >> 2;          // 0..15
  const int lq = (lane & 3) * 8;     // 0,8,16,24 (elems)
  const unsigned short* Asrc = A + (size_t)(m0 + lr) * K + lq;
  const unsigned short* Bsrc = BT + (size_t)(n0 + lr) * K + lq;

  f32x4 acc[8][3] = {};

  auto stage = [&](int buf, int t) {
    const int tc = t * 32;
    gload_lds16(Asrc + (size_t)(w * 16) * K + tc, &lds[buf][w * 512]);
    gload_lds16(Asrc + (size_t)(128 + w * 16) * K + tc, &lds[buf][4096 + w * 512]);
    gload_lds16(Bsrc + (size_t)(w * 16) * K + tc, &lds[buf][8192 + w * 512]);
    if (w < 4)
      gload_lds16(Bsrc + (size_t)(128 + w * 16) * K + tc, &lds[buf][12288 + w * 512]);
  };
  auto rdA = [&](int buf, int mi) {
    const int row = wr * 128 + mi * 16 + l15;
    return *(const u32x4*)&lds[buf][row * 32 + g * 8];
  };
  auto rdB = [&](int buf, int ni) {
    const int row = wc * 48 + ni * 16 + l15;
    return *(const u32x4*)&lds[buf][8192 + row * 32 + g * 8];
  };

  stage(0, 0);

  const int NT = K >> 5;   // 128
  for (int t = 0; t < NT; ++t) {
    const int cb_ = t & 1, nb_ = cb_ ^ 1;

    asm volatile("s_waitcnt vmcnt(0)" ::: "memory");
    __builtin_amdgcn_s_barrier();
    asm volatile("" ::: "memory");   // pin: stages stay below the barrier
    if (t + 1 < NT) stage(nb_, t + 1);

    u32x4 b0 = rdB(cb_, 0), b1 = rdB(cb_, 1), b2 = rdB(cb_, 2);
    __builtin_amdgcn_s_setprio(1);
#pragma unroll
    for (int mi = 0; mi < 8; ++mi) {
      u32x4 a = rdA(cb_, mi);
      acc[mi][0] = MFMA16(BC8(a), BC8(b0), acc[mi][0]);
      acc[mi][1] = MFMA16(BC8(a), BC8(b1), acc[mi][1]);
      acc[mi][2] = MFMA16(BC8(a), BC8(b2), acc[mi][2]);
    }
    __builtin_amdgcn_s_setprio(0);
  }

  const int crow0 = m0 + wr * 128;
  const int ccol0 = n0 + wc * 48;
#pragma unroll
  for (int mi = 0; mi < 8; ++mi)
#pragma unroll
    for (int ni = 0; ni < 3; ++ni)
#pragma unroll
      for (int r = 0; r < 4; ++r) {
        const size_t idx =
            (size_t)(crow0 + mi * 16 + g * 4 + r) * N + (ccol0 + ni * 16 + l15);
        Cout[idx] = f2bf(acc[mi][ni][r]);
      }
}

// ---------------------------------------------------------------------------
// GEMM2: 8-phase template, NIF=4 256x256, grid 256 = 1.0 CU-wave (~1296 TF).
// ---------------------------------------------------------------------------
template <int NIF, int OUTF32>
__global__ __launch_bounds__(512, 2) void gemm_p4(const unsigned short* __restrict__ A,
                                                  const unsigned short* __restrict__ BT,
                                                  void* __restrict__ Cout,
                                                  int M, int N, int K) {
  constexpr int BUFE = 16384 + NIF * 4096;
  constexpr int NR = NIF + 4;
  __shared__ __align__(16) unsigned short lds[2][BUFE];
  const int tid = threadIdx.x;
  const int lane = tid & 63;
  const int w = tid >> 6;
  const int wr = w >> 2;
  const int wc = w & 3;
  const int g = lane >> 4;
  const int l15 = lane & 15;

  const int nwg = gridDim.x;
  const int cpx = nwg >> 3;
  const int bid = blockIdx.x;
  const int swz = (bid & 7) * cpx + (bid >> 3);
  const int MT = M >> 8;
  const int m0 = (swz % MT) * 256;
  const int n0 = (swz / MT) * (NIF * 64);

  const int lrow = lane >> 3;
  const int lcol = ((lane & 7) ^ lrow) * 8;
  const unsigned short* Asrc = A + (size_t)(m0 + w * 8 + lrow) * K + lcol;
  const unsigned short* Bsrc = BT + (size_t)(n0 + w * 8 + lrow) * K + lcol;

  f32x4 acc[8][NIF] = {};

  auto stage = [&](int buf, int t, int r) {
    if (r < NIF) {
      const int rb = r * 64;
      gload_lds16(Bsrc + (size_t)rb * K + t * 64,
                  &lds[buf][16384 + (rb + w * 8) * 64]);
    } else {
      const int j = r - NIF;
      const int rb = (j & 1) * 128 + ((j >> 1) & 1) * 64;
      gload_lds16(Asrc + (size_t)rb * K + t * 64,
                  &lds[buf][(rb + w * 8) * 64]);
    }
  };
  auto rdA = [&](int buf, int mi, int ks) {
    const int row = wr * 128 + mi * 16 + l15;
    const int cb = (ks * 64 + g * 16) ^ ((l15 & 7) << 4);
    return *(const u32x4*)((const char*)&lds[buf][0] + row * 128 + cb);
  };
  auto rdB = [&](int buf, int ni, int ks) {
    const int row = wc * (NIF * 16) + ni * 16 + l15;
    const int cb = (ks * 64 + g * 16) ^ ((l15 & 7) << 4);
    return *(const u32x4*)((const char*)&lds[buf][0] + 32768 + row * 128 + cb);
  };

#pragma unroll
  for (int r = 0; r < NR; ++r) stage(0, 0, r);
  asm volatile("s_waitcnt vmcnt(2)" ::: "memory");
  __builtin_amdgcn_sched_barrier(0);
  __builtin_amdgcn_s_barrier();

  const int NT = K >> 6;
  for (int t = 0; t < NT; ++t) {
    const int cb_ = t & 1, nb_ = cb_ ^ 1;
    const bool pre = (t + 1 < NT);
    u32x4 bfr[NIF][2];

    // ---------------- P0 : mi 0,1 (+ all B frags) ----------------
    {
#pragma unroll
      for (int ni = 0; ni < NIF; ++ni) {
        bfr[ni][0] = rdB(cb_, ni, 0);
        bfr[ni][1] = rdB(cb_, ni, 1);
      }
      u32x4 a00 = rdA(cb_, 0, 0), a01 = rdA(cb_, 0, 1);
      u32x4 a10 = rdA(cb_, 1, 0), a11 = rdA(cb_, 1, 1);
      if (pre) { stage(nb_, t + 1, 0); stage(nb_, t + 1, 1); }
      __builtin_amdgcn_sched_barrier(0);
      __builtin_amdgcn_s_barrier();
      asm volatile("s_waitcnt lgkmcnt(0)" ::: "memory");
      __builtin_amdgcn_sched_barrier(0);
      __builtin_amdgcn_s_setprio(1);
#pragma unroll
      for (int ni = 0; ni < NIF; ++ni) {
        acc[0][ni] = MFMA16(BC8(a00), BC8(bfr[ni][0]), acc[0][ni]);
        acc[0][ni] = MFMA16(BC8(a01), BC8(bfr[ni][1]), acc[0][ni]);
        acc[1][ni] = MFMA16(BC8(a10), BC8(bfr[ni][0]), acc[1][ni]);
        acc[1][ni] = MFMA16(BC8(a11), BC8(bfr[ni][1]), acc[1][ni]);
      }
      __builtin_amdgcn_s_setprio(0);
      __builtin_amdgcn_sched_barrier(0);
      __builtin_amdgcn_s_barrier();
    }
    // ---------------- P1 : mi 2,3 ----------------
    {
      u32x4 a00 = rdA(cb_, 2, 0), a01 = rdA(cb_, 2, 1);
      u32x4 a10 = rdA(cb_, 3, 0), a11 = rdA(cb_, 3, 1);
      if (pre) {
        stage(nb_, t + 1, 2); stage(nb_, t + 1, 3);
        asm volatile("s_waitcnt vmcnt(4)" ::: "memory");
      } else {
        asm volatile("s_waitcnt vmcnt(0)" ::: "memory");
      }
      __builtin_amdgcn_sched_barrier(0);
      __builtin_amdgcn_s_barrier();
      asm volatile("s_waitcnt lgkmcnt(0)" ::: "memory");
      __builtin_amdgcn_sched_barrier(0);
      __builtin_amdgcn_s_setprio(1);
#pragma unroll
      for (int ni = 0; ni < NIF; ++ni) {
        acc[2][ni] = MFMA16(BC8(a00), BC8(bfr[ni][0]), acc[2][ni]);
        acc[2][ni] = MFMA16(BC8(a01), BC8(bfr[ni][1]), acc[2][ni]);
        acc[3][ni] = MFMA16(BC8(a10), BC8(bfr[ni][0]), acc[3][ni]);
        acc[3][ni] = MFMA16(BC8(a11), BC8(bfr[ni][1]), acc[3][ni]);
      }
      __builtin_amdgcn_s_setprio(0);
      __builtin_amdgcn_sched_barrier(0);
      __builtin_amdgcn_s_barrier();
    }
    // ---------------- P2 : mi 4,5 ----------------
    {
      u32x4 a00 = rdA(cb_, 4, 0), a01 = rdA(cb_, 4, 1);
      u32x4 a10 = rdA(cb_, 5, 0), a11 = rdA(cb_, 5, 1);
      if (pre) { stage(nb_, t + 1, 4); stage(nb_, t + 1, 5); }
      __builtin_amdgcn_sched_barrier(0);
      __builtin_amdgcn_s_barrier();
      asm volatile("s_waitcnt lgkmcnt(0)" ::: "memory");
      __builtin_amdgcn_sched_barrier(0);
      __builtin_amdgcn_s_setprio(1);
#pragma unroll
      for (int ni = 0; ni < NIF; ++ni) {
        acc[4][ni] = MFMA16(BC8(a00), BC8(bfr[ni][0]), acc[4][ni]);
        acc[4][ni] = MFMA16(BC8(a01), BC8(bfr[ni][1]), acc[4][ni]);
        acc[5][ni] = MFMA16(BC8(a10), BC8(bfr[ni][0]), acc[5][ni]);
        acc[5][ni] = MFMA16(BC8(a11), BC8(bfr[ni][1]), acc[5][ni]);
      }
      __builtin_amdgcn_s_setprio(0);
      __builtin_amdgcn_sched_barrier(0);
      __builtin_amdgcn_s_barrier();
    }
    // ---------------- P3 : mi 6,7 ----------------
    {
      u32x4 a00 = rdA(cb_, 6, 0), a01 = rdA(cb_, 6, 1);
      u32x4 a10 = rdA(cb_, 7, 0), a11 = rdA(cb_, 7, 1);
      if (pre) {
        stage(nb_, t + 1, 6);
        if (NR == 8) stage(nb_, t + 1, 7);
        asm volatile("s_waitcnt vmcnt(2)" ::: "memory");
      }
      __builtin_amdgcn_sched_barrier(0);
      __builtin_amdgcn_s_barrier();
      asm volatile("s_waitcnt lgkmcnt(0)" ::: "memory");
      __builtin_amdgcn_sched_barrier(0);
      __builtin_amdgcn_s_setprio(1);
#pragma unroll
      for (int ni = 0; ni < NIF; ++ni) {
        acc[6][ni] = MFMA16(BC8(a00), BC8(bfr[ni][0]), acc[6][ni]);
        acc[6][ni] = MFMA16(BC8(a01), BC8(bfr[ni][1]), acc[6][ni]);
        acc[7][ni] = MFMA16(BC8(a10), BC8(bfr[ni][0]), acc[7][ni]);
        acc[7][ni] = MFMA16(BC8(a11), BC8(bfr[ni][1]), acc[7][ni]);
      }
      __builtin_amdgcn_s_setprio(0);
      __builtin_amdgcn_sched_barrier(0);
      __builtin_amdgcn_s_barrier();
    }
  }

  const int crow0 = m0 + wr * 128;
  const int ccol0 = n0 + wc * (NIF * 16);
#pragma unroll
  for (int mi = 0; mi < 8; ++mi)
#pragma unroll
    for (int ni = 0; ni < NIF; ++ni)
#pragma unroll
      for (int r = 0; r < 4; ++r) {
        const size_t idx =
            (size_t)(crow0 + mi * 16 + g * 4 + r) * N + (ccol0 + ni * 16 + l15);
        if constexpr (OUTF32) ((float*)Cout)[idx] = acc[mi][ni][r];
        else ((unsigned short*)Cout)[idx] = f2bf(acc[mi][ni][r]);
      }
}

// ---------------------------------------------------------------------------
// Flash attention, GQA, causal + sliding window 1024, fused Q-RoPE.
// 1D grid 512 with heavy/light decode: bid<256 -> qb 4..7 (20 tiles each),
// bid>=256 -> qb 3..0 (16..4 tiles) so each CU hosts one heavy + one light.
// ---------------------------------------------------------------------------
__global__ __launch_bounds__(512, 2) void attn_kernel(const unsigned short* __restrict__ qkv,
                                                      unsigned short* __restrict__ aout,
                                                      const int* __restrict__ pos) {
  __shared__ __align__(16) unsigned short smem[35840];   // 2 buffers, 70 KiB

  const int tid = threadIdx.x;
  const int lane = tid & 63;
  const int w = tid >> 6;
  const int hi = lane >> 5;
  const int l31 = lane & 31;

  // load-balance decode (qb x h x b), heavy first
  const int bid = blockIdx.x;
  const int half = bid >> 8;             // 0: heavy, 1: light
  const int r_ = bid & 255;
  const int qb = half ? ((r_ & 3) ^ 3) : (4 + (r_ & 3));
  const int h = (r_ >> 2) & 31;
  const int b = r_ >> 7;

  const int q0 = qb * 256;
  const int kh = h >> 2;
  const size_t tokbase = (size_t)b * 2048;
  const int qw0 = q0 + w * 32;
  const int qg = qw0 + l31;

  short8 qf[8];
  {
    const unsigned short* qp = qkv + (tokbase + qg) * 6144 + h * 128;
#pragma unroll
    for (int ks8 = 0; ks8 < 8; ++ks8)
      qf[ks8] = BC8(*(const u32x4*)(qp + ks8 * 16 + hi * 8));
    const float fp = (float)pos[qg];
#pragma unroll
    for (int ks8 = 0; ks8 < 4; ++ks8)
#pragma unroll
      for (int j = 0; j < 8; ++j) {
        const int d = ks8 * 16 + hi * 8 + j;
        const float x1 = bf2f((unsigned short)qf[ks8][j]);
        const float x2 = bf2f((unsigned short)qf[ks8 + 4][j]);
        const float ang = fp * exp2f(-(float)d * 0.2076205059304601f);
        float c, sn;
        __sincosf(ang, &sn, &c);
        qf[ks8][j]     = (short)f2bf(x1 * c - x2 * sn);
        qf[ks8 + 4][j] = (short)f2bf(x2 * c + x1 * sn);
      }
  }

  const int c0key = tid >> 4, c0col = tid & 15;
  const int c1key = (tid + 512) >> 4, c1col = tid & 15;

  u32x4 kreg[2], vreg[2];
  const unsigned short* kvK = qkv + tokbase * 6144 + 4096 + kh * 128;

  const int t0 = (q0 >= 1024 ? (q0 - 1023) >> 6 : 0);
  const int t1 = (q0 + 255) >> 6;

  {
    const unsigned short* kb = kvK + (size_t)(t0 * 64) * 6144;
    kreg[0] = *(const u32x4*)(kb + (size_t)c0key * 6144 + c0col * 8);
    kreg[1] = *(const u32x4*)(kb + (size_t)c1key * 6144 + c1col * 8);
    vreg[0] = *(const u32x4*)(kb + (size_t)c0key * 6144 + 1024 + c0col * 8);
    vreg[1] = *(const u32x4*)(kb + (size_t)c1key * 6144 + 1024 + c1col * 8);
  }

  float m_run = -1e30f, l_run = 0.0f;
  f32x16 o_acc[4] = {};

  for (int kt = t0; kt <= t1; ++kt) {
    const int cur = (kt - t0) & 1;
    unsigned short* kdst = &smem[(cur)*17920];
    unsigned short* vdst = kdst + 8704;

    if (kt == t0) {
      *(u32x4*)&kdst[c0key * 136 + c0col * 8] = kreg[0];
      *(u32x4*)&kdst[c1key * 136 + c1col * 8] = kreg[1];
#pragma unroll
      for (int e = 0; e < 8; ++e) {
        const int e0 = (e + c0col) & 7;
        const int e1 = (e + c1col) & 7;
        vdst[(c0col * 8 + e0) * 72 + c0key] =
            (unsigned short)(vreg[0][e0 >> 1] >> ((e0 & 1) * 16));
        vdst[(c1col * 8 + e1) * 72 + c1key] =
            (unsigned short)(vreg[1][e1 >> 1] >> ((e1 & 1) * 16));
      }
      if (kt < t1) {
        const unsigned short* kb = kvK + (size_t)((kt + 1) * 64) * 6144;
        kreg[0] = *(const u32x4*)(kb + (size_t)c0key * 6144 + c0col * 8);
        kreg[1] = *(const u32x4*)(kb + (size_t)c1key * 6144 + c1col * 8);
        vreg[0] = *(const u32x4*)(kb + (size_t)c0key * 6144 + 1024 + c0col * 8);
        vreg[1] = *(const u32x4*)(kb + (size_t)c1key * 6144 + 1024 + c1col * 8);
      }
      __syncthreads();
    }

    if (kt < t1) {
      unsigned short* kdn = &smem[(cur ^ 1) * 17920];
      unsigned short* vdn = kdn + 8704;
      *(u32x4*)&kdn[c0key * 136 + c0col * 8] = kreg[0];
      *(u32x4*)&kdn[c1key * 136 + c1col * 8] = kreg[1];
#pragma unroll
      for (int e = 0; e < 8; ++e) {
        const int e0 = (e + c0col) & 7;
        const int e1 = (e + c1col) & 7;
        vdn[(c0col * 8 + e0) * 72 + c0key] =
            (unsigned short)(vreg[0][e0 >> 1] >> ((e0 & 1) * 16));
        vdn[(c1col * 8 + e1) * 72 + c1key] =
            (unsigned short)(vreg[1][e1 >> 1] >> ((e1 & 1) * 16));
      }
      if (kt + 2 <= t1) {
        const unsigned short* kb = kvK + (size_t)((kt + 2) * 64) * 6144;
        kreg[0] = *(const u32x4*)(kb + (size_t)c0key * 6144 + c0col * 8);
        kreg[1] = *(const u32x4*)(kb + (size_t)c1key * 6144 + c1col * 8);
        vreg[0] = *(const u32x4*)(kb + (size_t)c0key * 6144 + 1024 + c0col * 8);
        vreg[1] = *(const u32x4*)(kb + (size_t)c1key * 6144 + 1024 + c1col * 8);
      }
    }

    const int ktb = kt * 64;
    if (ktb <= qw0 + 31 && ktb + 63 >= qw0 - 1023) {
      const unsigned short* kb = &smem[cur * 17920];
      const unsigned short* vb = kb + 8704;

      f32x16 s0 = {}, s1 = {};
      const int arow = l31 * 136 + hi * 8;
#pragma unroll
      for (int ks8 = 0; ks8 < 8; ++ks8) {
        u32x4 a0 = *(const u32x4*)&kb[arow + ks8 * 16];
        u32x4 a1 = *(const u32x4*)&kb[arow + 32 * 136 + ks8 * 16];
        s0 = MFMA32(BC8(a0), qf[ks8], s0);
        s1 = MFMA32(BC8(a1), qf[ks8], s1);
      }

      const float scale = 0.08838834764831845f;
      float pv[32];
      const bool need_mask = !(ktb + 63 <= qw0 && ktb >= qw0 - 992);
      if (need_mask) {
#pragma unroll
        for (int r = 0; r < 16; ++r) {
          const int key0 = ktb + ((r & 3) + 8 * (r >> 2) + 4 * hi);
          const int key1 = key0 + 32;
          pv[r]      = (key0 <= qg && qg - key0 < 1024) ? s0[r] * scale : -1e30f;
          pv[16 + r] = (key1 <= qg && qg - key1 < 1024) ? s1[r] * scale : -1e30f;
        }
      } else {
#pragma unroll
        for (int r = 0; r < 16; ++r) {
          pv[r] = s0[r] * scale;
          pv[16 + r] = s1[r] * scale;
        }
      }

      float tm = -1e30f;
#pragma unroll
      for (int i = 0; i < 32; ++i) tm = fmaxf(tm, pv[i]);
      tm = fmaxf(tm, __shfl_xor(tm, 32, 64));
      if (__any(tm > m_run + 8.0f)) {
        const float mn = fmaxf(fmaxf(m_run, tm), -1e20f);
        const float scl = __expf(m_run - mn);
#pragma unroll
        for (int d = 0; d < 4; ++d) o_acc[d] *= scl;
        l_run *= scl;
        m_run = mn;
      }
      float lsum = 0.0f;
#pragma unroll
      for (int i = 0; i < 32; ++i) {
        pv[i] = __expf(pv[i] - m_run);
        lsum += pv[i];
      }
      l_run += lsum + __shfl_xor(lsum, 32, 64);

      u32x4 paf[4];
#pragma unroll
      for (int ks = 0; ks < 4; ++ks) {
        const int base = (ks >> 1) * 16 + (ks & 1) * 8;
        auto rA = __builtin_amdgcn_permlane32_swap(
            (int)cvtpk_bf16(pv[base + 0], pv[base + 1]),
            (int)cvtpk_bf16(pv[base + 4], pv[base + 5]), false, false);
        auto rB = __builtin_amdgcn_permlane32_swap(
            (int)cvtpk_bf16(pv[base + 2], pv[base + 3]),
            (int)cvtpk_bf16(pv[base + 6], pv[base + 7]), false, false);
        paf[ks][0] = (unsigned int)rA[0];
        paf[ks][1] = (unsigned int)rB[0];
        paf[ks][2] = (unsigned int)rA[1];
        paf[ks][3] = (unsigned int)rB[1];
      }

#pragma unroll
      for (int dblk = 0; dblk < 4; ++dblk) {
        const int vrow = (dblk * 32 + l31) * 72 + hi * 8;
#pragma unroll
        for (int ks = 0; ks < 4; ++ks) {
          u32x4 vf = *(const u32x4*)&vb[vrow + ks * 16];
          o_acc[dblk] = MFMA32(BC8(vf), BC8(paf[ks]), o_acc[dblk]);
        }
      }
    }

    __syncthreads();
  }

  const float rl = 1.0f / l_run;
  unsigned short* ob = &smem[w * 4352];
#pragma unroll
  for (int dblk = 0; dblk < 4; ++dblk)
#pragma unroll
    for (int rq = 0; rq < 4; ++rq) {
      u16x4 pk;
#pragma unroll
      for (int i = 0; i < 4; ++i) pk[i] = f2bf(o_acc[dblk][rq * 4 + i] * rl);
      *(u16x4*)&ob[l31 * 136 + dblk * 32 + rq * 8 + hi * 4] = pk;
    }
  __syncthreads();

  unsigned short* gout = aout + (tokbase + q0 + w * 32) * 4096 + h * 128;
#pragma unroll
  for (int r4 = 0; r4 < 8; ++r4) {
    const int row = r4 * 4 + (lane >> 4);
    u32x4 val = *(const u32x4*)&ob[row * 136 + (lane & 15) * 8];
    *(u32x4*)(gout + (size_t)row * 4096 + (lane & 15) * 8) = val;
  }
}

// ---------------------------------------------------------------------------
// launch
// ---------------------------------------------------------------------------
extern "C" void kernel_launch(void* const* d_in, const int* in_sizes, int n_in,
                              void* d_out, int out_size, void* d_ws, size_t ws_size,
                              hipStream_t stream) {
  (void)in_sizes; (void)n_in; (void)out_size; (void)ws_size;
  const float* hs   = (const float*)d_in[0];   // [2,2048,4096]
  const float* wqkv = (const float*)d_in[1];   // [4096,6144]
  const float* wo   = (const float*)d_in[2];   // [4096,4096]
  const int*   pos  = (const int*)d_in[3];     // [2048]
  float* out = (float*)d_out;                  // [2,2048,4096] fp32

  char* ws = (char*)d_ws;
  unsigned short* qkvb = (unsigned short*)ws;                // [4096][6144] bf16
  unsigned short* wT   = (unsigned short*)(ws + 50331648);   // weightT bf16
  unsigned short* hsb  = (unsigned short*)(ws + 100663296);  // [4096][4096] bf16

  cvt1<<<40960, 256, 0, stream>>>(hs, wqkv, hsb, wT);
  // GEMM1: BK=32 tile 256x192, 2 blocks/CU, grid 512 (186.5 us measured)
  gemm_k32<<<512, 512, 0, stream>>>(hsb, wT, qkvb, 4096, 6144, 4096);
  rope_cvtwo<<<24576, 256, 0, stream>>>(qkvb, pos, wo, wT);
  // attn: 1D grid, heavy-then-light order for balanced CU pairing
  attn_kernel<<<512, 512, 0, stream>>>(qkvb, hsb, pos);
  // GEMM2: 8-phase NIF4 256x256, grid 256 = 1.0 CU-wave (~106 us, 1296 TF)
  gemm_p4<4, 1><<<256, 512, 0, stream>>>(hsb, wT, out, 4096, 4096, 4096);
}

// Round 17
// 470.040 us; speedup vs baseline: 1.0471x; 1.0030x over previous
//
#include <hip/hip_runtime.h>

// ---------------------------------------------------------------------------
// MixtralAttention on MI355X (gfx950)
// B=2, S=2048, HID=4096, NH=32, NKV=8, HD=128, WINDOW=1024, THETA=10000
// Build = R16 (best, 471.4 us) + coalesced 64x64 transpose:
//   fp32 reads as f32x4 (256B/row-group), LDS staged pre-transposed bf16
//   (stride 68 shorts), output written as u16x4 -> 128B coalesced segments.
// ---------------------------------------------------------------------------

typedef __attribute__((ext_vector_type(8))) short short8;       // bf16x8 frag
typedef __attribute__((ext_vector_type(4))) float f32x4;        // 16x16 acc
typedef __attribute__((ext_vector_type(16))) float f32x16;      // 32x32 acc
typedef __attribute__((ext_vector_type(4))) unsigned int u32x4; // 16B load
typedef __attribute__((ext_vector_type(4))) unsigned short u16x4;

__device__ __forceinline__ unsigned short f2bf(float f) {
  unsigned int u = __builtin_bit_cast(unsigned int, f);
  u = u + 0x7fffu + ((u >> 16) & 1u);   // round-to-nearest-even
  return (unsigned short)(u >> 16);
}
__device__ __forceinline__ float bf2f(unsigned short h) {
  unsigned int u = ((unsigned int)h) << 16;
  return __builtin_bit_cast(float, u);
}
__device__ __forceinline__ unsigned int cvtpk_bf16(float lo, float hi) {
  unsigned int r;
  asm("v_cvt_pk_bf16_f32 %0, %1, %2" : "=v"(r) : "v"(lo), "v"(hi));
  return r;
}

__device__ __forceinline__ void gload_lds16(const unsigned short* g, unsigned short* l) {
  __builtin_amdgcn_global_load_lds(
      (const __attribute__((address_space(1))) unsigned int*)g,
      (__attribute__((address_space(3))) unsigned int*)l, 16, 0, 0);
}

#define MFMA16(A, B, C) __builtin_amdgcn_mfma_f32_16x16x32_bf16((A), (B), (C), 0, 0, 0)
#define MFMA32(A, B, C) __builtin_amdgcn_mfma_f32_32x32x16_bf16((A), (B), (C), 0, 0, 0)
#define BC8(x) __builtin_bit_cast(short8, (x))

// ---------------------------------------------------------------------------
// 64x64 fp32 -> bf16 transpose tile. 256 threads.
// Load: f32x4 per thread (rows r0+p*16+ri, cols c0+ci4..+3), stage into
// tl[c][r] (stride 68 shorts, 8B-aligned). Write: u16x4 per thread ->
// out rows c0+p*16+ri get 128B coalesced segments per 16 lanes.
// ---------------------------------------------------------------------------
__device__ __forceinline__ void transpose64(const float* __restrict__ in,
                                            unsigned short* __restrict__ out,
                                            int R, int C, int r0, int c0,
                                            int tid, unsigned short* tl) {
  const int ri = tid >> 4;          // 0..15
  const int ci4 = (tid & 15) * 4;   // 0,4,..,60
#pragma unroll
  for (int p = 0; p < 4; ++p) {
    f32x4 v = *(const f32x4*)(in + (size_t)(r0 + p * 16 + ri) * C + c0 + ci4);
#pragma unroll
    for (int j = 0; j < 4; ++j)
      tl[(ci4 + j) * 68 + p * 16 + ri] = f2bf(v[j]);
  }
  __syncthreads();
#pragma unroll
  for (int p = 0; p < 4; ++p) {
    u16x4 v = *(const u16x4*)&tl[(p * 16 + ri) * 68 + ci4];
    *(u16x4*)(out + (size_t)(c0 + p * 16 + ri) * R + r0 + ci4) = v;
  }
}

// ---------------------------------------------------------------------------
// merged: transpose64(wqkv -> wqkvT) + cvt_plain(hs -> hsb)
// grid 22528 = 6144 (96x64 tiles) + 16384 (plain)
// ---------------------------------------------------------------------------
__global__ __launch_bounds__(256) void cvt1(const float* __restrict__ hs,
                                            const float* __restrict__ wqkv,
                                            unsigned short* __restrict__ hsb,
                                            unsigned short* __restrict__ wT) {
  __shared__ __align__(16) unsigned short tl[64 * 68];
  const int bid = blockIdx.x;
  if (bid < 6144) {
    const int c0 = (bid % 96) * 64, r0 = (bid / 96) * 64;  // R=4096, C=6144
    transpose64(wqkv, wT, 4096, 6144, r0, c0, threadIdx.x, tl);
  } else {
    const int i = ((bid - 6144) * 256 + threadIdx.x) * 4;
    f32x4 v = *(const f32x4*)(hs + i);
    u16x4 o;
#pragma unroll
    for (int j = 0; j < 4; ++j) o[j] = f2bf(v[j]);
    *(u16x4*)(hsb + i) = o;
  }
}

// ---------------------------------------------------------------------------
// merged: rope_k (K heads in qkv) + transpose64(wo -> woT)
// grid 12288 = 8192 (rope) + 4096 (64x64 tiles)
// ---------------------------------------------------------------------------
__global__ __launch_bounds__(256) void rope_cvtwo(unsigned short* __restrict__ qkv,
                                                  const int* __restrict__ pos,
                                                  const float* __restrict__ wo,
                                                  unsigned short* __restrict__ wT) {
  __shared__ __align__(16) unsigned short tl[64 * 68];
  const int bid = blockIdx.x;
  if (bid < 8192) {
    const int idx = bid * 256 + threadIdx.x;   // < 4096*8*64
    const int d = idx & 63;
    const int hh = (idx >> 6) & 7;
    const int tok = idx >> 9;
    const int s = tok & 2047;
    unsigned short* p = qkv + (size_t)tok * 6144 + 4096 + hh * 128 + d;
    const float x1 = bf2f(p[0]);
    const float x2 = bf2f(p[64]);
    const float inv = exp2f(-(float)d * 0.2076205059304601f);
    const float ang = (float)pos[s] * inv;
    const float c = cosf(ang), sn = sinf(ang);
    p[0]  = f2bf(x1 * c - x2 * sn);
    p[64] = f2bf(x2 * c + x1 * sn);
  } else {
    const int b2 = bid - 8192;
    const int c0 = (b2 & 63) * 64, r0 = (b2 >> 6) * 64;   // R=C=4096
    transpose64(wo, wT, 4096, 4096, r0, c0, threadIdx.x, tl);
  }
}

// ---------------------------------------------------------------------------
// GEMM1: C[M,N] = A[M,K] * B^T[N,K], tile 256x192 (NIF=3), BK=32, grid 512.
// LDS 2 x 28 KB -> 2 blocks/CU; cross-block overlap hides the vmcnt(0).
// Per K-tile: { vmcnt(0); s_barrier; stage(t+1); 24 MFMA }. (R12/R14-exact)
// ---------------------------------------------------------------------------
__global__ __launch_bounds__(512, 4) void gemm_k32(const unsigned short* __restrict__ A,
                                                   const unsigned short* __restrict__ BT,
                                                   unsigned short* __restrict__ Cout,
                                                   int M, int N, int K) {
  __shared__ __align__(16) unsigned short lds[2][14336];   // 2 x 28 KB
  const int tid = threadIdx.x;
  const int lane = tid & 63;
  const int w = tid >> 6;          // wave 0..7
  const int wr = w >> 2;           // 0..1 (M)
  const int wc = w & 3;            // 0..3 (N)
  const int g = lane >> 4;
  const int l15 = lane & 15;

  const int nwg = gridDim.x;
  const int cpx = nwg >> 3;
  const int bid = blockIdx.x;
  const int swz = (bid & 7) * cpx + (bid >> 3);
  const int MT = M >> 8;
  const int m0 = (swz % MT) * 256;
  const int n0 = (swz / MT) * 192;

  const int lr = lane >> 2;          // 0..15
  const int lq = (lane & 3) * 8;     // 0,8,16,24 (elems)
  const unsigned short* Asrc = A + (size_t)(m0 + lr) * K + lq;
  const unsigned short* Bsrc = BT + (size_t)(n0 + lr) * K + lq;

  f32x4 acc[8][3] = {};

  auto stage = [&](int buf, int t) {
    const int tc = t * 32;
    gload_lds16(Asrc + (size_t)(w * 16) * K + tc, &lds[buf][w * 512]);
    gload_lds16(Asrc + (size_t)(128 + w * 16) * K + tc, &lds[buf][4096 + w * 512]);
    gload_lds16(Bsrc + (size_t)(w * 16) * K + tc, &lds[buf][8192 + w * 512]);
    if (w < 4)
      gload_lds16(Bsrc + (size_t)(128 + w * 16) * K + tc, &lds[buf][12288 + w * 512]);
  };
  auto rdA = [&](int buf, int mi) {
    const int row = wr * 128 + mi * 16 + l15;
    return *(const u32x4*)&lds[buf][row * 32 + g * 8];
  };
  auto rdB = [&](int buf, int ni) {
    const int row = wc * 48 + ni * 16 + l15;
    return *(const u32x4*)&lds[buf][8192 + row * 32 + g * 8];
  };

  stage(0, 0);

  const int NT = K >> 5;   // 128
  for (int t = 0; t < NT; ++t) {
    const int cb_ = t & 1, nb_ = cb_ ^ 1;

    asm volatile("s_waitcnt vmcnt(0)" ::: "memory");
    __builtin_amdgcn_s_barrier();
    asm volatile("" ::: "memory");   // pin: stages stay below the barrier
    if (t + 1 < NT) stage(nb_, t + 1);

    u32x4 b0 = rdB(cb_, 0), b1 = rdB(cb_, 1), b2 = rdB(cb_, 2);
    __builtin_amdgcn_s_setprio(1);
#pragma unroll
    for (int mi = 0; mi < 8; ++mi) {
      u32x4 a = rdA(cb_, mi);
      acc[mi][0] = MFMA16(BC8(a), BC8(b0), acc[mi][0]);
      acc[mi][1] = MFMA16(BC8(a), BC8(b1), acc[mi][1]);
      acc[mi][2] = MFMA16(BC8(a), BC8(b2), acc[mi][2]);
    }
    __builtin_amdgcn_s_setprio(0);
  }

  const int crow0 = m0 + wr * 128;
  const int ccol0 = n0 + wc * 48;
#pragma unroll
  for (int mi = 0; mi < 8; ++mi)
#pragma unroll
    for (int ni = 0; ni < 3; ++ni)
#pragma unroll
      for (int r = 0; r < 4; ++r) {
        const size_t idx =
            (size_t)(crow0 + mi * 16 + g * 4 + r) * N + (ccol0 + ni * 16 + l15);
        Cout[idx] = f2bf(acc[mi][ni][r]);
      }
}

// ---------------------------------------------------------------------------
// GEMM2: 8-phase template, NIF=4 256x256, grid 256 = 1.0 CU-wave (~1296 TF).
// ---------------------------------------------------------------------------
template <int NIF, int OUTF32>
__global__ __launch_bounds__(512, 2) void gemm_p4(const unsigned short* __restrict__ A,
                                                  const unsigned short* __restrict__ BT,
                                                  void* __restrict__ Cout,
                                                  int M, int N, int K) {
  constexpr int BUFE = 16384 + NIF * 4096;
  constexpr int NR = NIF + 4;
  __shared__ __align__(16) unsigned short lds[2][BUFE];
  const int tid = threadIdx.x;
  const int lane = tid & 63;
  const int w = tid >> 6;
  const int wr = w >> 2;
  const int wc = w & 3;
  const int g = lane >> 4;
  const int l15 = lane & 15;

  const int nwg = gridDim.x;
  const int cpx = nwg >> 3;
  const int bid = blockIdx.x;
  const int swz = (bid & 7) * cpx + (bid >> 3);
  const int MT = M >> 8;
  const int m0 = (swz % MT) * 256;
  const int n0 = (swz / MT) * (NIF * 64);

  const int lrow = lane >> 3;
  const int lcol = ((lane & 7) ^ lrow) * 8;
  const unsigned short* Asrc = A + (size_t)(m0 + w * 8 + lrow) * K + lcol;
  const unsigned short* Bsrc = BT + (size_t)(n0 + w * 8 + lrow) * K + lcol;

  f32x4 acc[8][NIF] = {};

  auto stage = [&](int buf, int t, int r) {
    if (r < NIF) {
      const int rb = r * 64;
      gload_lds16(Bsrc + (size_t)rb * K + t * 64,
                  &lds[buf][16384 + (rb + w * 8) * 64]);
    } else {
      const int j = r - NIF;
      const int rb = (j & 1) * 128 + ((j >> 1) & 1) * 64;
      gload_lds16(Asrc + (size_t)rb * K + t * 64,
                  &lds[buf][(rb + w * 8) * 64]);
    }
  };
  auto rdA = [&](int buf, int mi, int ks) {
    const int row = wr * 128 + mi * 16 + l15;
    const int cb = (ks * 64 + g * 16) ^ ((l15 & 7) << 4);
    return *(const u32x4*)((const char*)&lds[buf][0] + row * 128 + cb);
  };
  auto rdB = [&](int buf, int ni, int ks) {
    const int row = wc * (NIF * 16) + ni * 16 + l15;
    const int cb = (ks * 64 + g * 16) ^ ((l15 & 7) << 4);
    return *(const u32x4*)((const char*)&lds[buf][0] + 32768 + row * 128 + cb);
  };

#pragma unroll
  for (int r = 0; r < NR; ++r) stage(0, 0, r);
  asm volatile("s_waitcnt vmcnt(2)" ::: "memory");
  __builtin_amdgcn_sched_barrier(0);
  __builtin_amdgcn_s_barrier();

  const int NT = K >> 6;
  for (int t = 0; t < NT; ++t) {
    const int cb_ = t & 1, nb_ = cb_ ^ 1;
    const bool pre = (t + 1 < NT);
    u32x4 bfr[NIF][2];

    // ---------------- P0 : mi 0,1 (+ all B frags) ----------------
    {
#pragma unroll
      for (int ni = 0; ni < NIF; ++ni) {
        bfr[ni][0] = rdB(cb_, ni, 0);
        bfr[ni][1] = rdB(cb_, ni, 1);
      }
      u32x4 a00 = rdA(cb_, 0, 0), a01 = rdA(cb_, 0, 1);
      u32x4 a10 = rdA(cb_, 1, 0), a11 = rdA(cb_, 1, 1);
      if (pre) { stage(nb_, t + 1, 0); stage(nb_, t + 1, 1); }
      __builtin_amdgcn_sched_barrier(0);
      __builtin_amdgcn_s_barrier();
      asm volatile("s_waitcnt lgkmcnt(0)" ::: "memory");
      __builtin_amdgcn_sched_barrier(0);
      __builtin_amdgcn_s_setprio(1);
#pragma unroll
      for (int ni = 0; ni < NIF; ++ni) {
        acc[0][ni] = MFMA16(BC8(a00), BC8(bfr[ni][0]), acc[0][ni]);
        acc[0][ni] = MFMA16(BC8(a01), BC8(bfr[ni][1]), acc[0][ni]);
        acc[1][ni] = MFMA16(BC8(a10), BC8(bfr[ni][0]), acc[1][ni]);
        acc[1][ni] = MFMA16(BC8(a11), BC8(bfr[ni][1]), acc[1][ni]);
      }
      __builtin_amdgcn_s_setprio(0);
      __builtin_amdgcn_sched_barrier(0);
      __builtin_amdgcn_s_barrier();
    }
    // ---------------- P1 : mi 2,3 ----------------
    {
      u32x4 a00 = rdA(cb_, 2, 0), a01 = rdA(cb_, 2, 1);
      u32x4 a10 = rdA(cb_, 3, 0), a11 = rdA(cb_, 3, 1);
      if (pre) {
        stage(nb_, t + 1, 2); stage(nb_, t + 1, 3);
        asm volatile("s_waitcnt vmcnt(4)" ::: "memory");
      } else {
        asm volatile("s_waitcnt vmcnt(0)" ::: "memory");
      }
      __builtin_amdgcn_sched_barrier(0);
      __builtin_amdgcn_s_barrier();
      asm volatile("s_waitcnt lgkmcnt(0)" ::: "memory");
      __builtin_amdgcn_sched_barrier(0);
      __builtin_amdgcn_s_setprio(1);
#pragma unroll
      for (int ni = 0; ni < NIF; ++ni) {
        acc[2][ni] = MFMA16(BC8(a00), BC8(bfr[ni][0]), acc[2][ni]);
        acc[2][ni] = MFMA16(BC8(a01), BC8(bfr[ni][1]), acc[2][ni]);
        acc[3][ni] = MFMA16(BC8(a10), BC8(bfr[ni][0]), acc[3][ni]);
        acc[3][ni] = MFMA16(BC8(a11), BC8(bfr[ni][1]), acc[3][ni]);
      }
      __builtin_amdgcn_s_setprio(0);
      __builtin_amdgcn_sched_barrier(0);
      __builtin_amdgcn_s_barrier();
    }
    // ---------------- P2 : mi 4,5 ----------------
    {
      u32x4 a00 = rdA(cb_, 4, 0), a01 = rdA(cb_, 4, 1);
      u32x4 a10 = rdA(cb_, 5, 0), a11 = rdA(cb_, 5, 1);
      if (pre) { stage(nb_, t + 1, 4); stage(nb_, t + 1, 5); }
      __builtin_amdgcn_sched_barrier(0);
      __builtin_amdgcn_s_barrier();
      asm volatile("s_waitcnt lgkmcnt(0)" ::: "memory");
      __builtin_amdgcn_sched_barrier(0);
      __builtin_amdgcn_s_setprio(1);
#pragma unroll
      for (int ni = 0; ni < NIF; ++ni) {
        acc[4][ni] = MFMA16(BC8(a00), BC8(bfr[ni][0]), acc[4][ni]);
        acc[4][ni] = MFMA16(BC8(a01), BC8(bfr[ni][1]), acc[4][ni]);
        acc[5][ni] = MFMA16(BC8(a10), BC8(bfr[ni][0]), acc[5][ni]);
        acc[5][ni] = MFMA16(BC8(a11), BC8(bfr[ni][1]), acc[5][ni]);
      }
      __builtin_amdgcn_s_setprio(0);
      __builtin_amdgcn_sched_barrier(0);
      __builtin_amdgcn_s_barrier();
    }
    // ---------------- P3 : mi 6,7 ----------------
    {
      u32x4 a00 = rdA(cb_, 6, 0), a01 = rdA(cb_, 6, 1);
      u32x4 a10 = rdA(cb_, 7, 0), a11 = rdA(cb_, 7, 1);
      if (pre) {
        stage(nb_, t + 1, 6);
        if (NR == 8) stage(nb_, t + 1, 7);
        asm volatile("s_waitcnt vmcnt(2)" ::: "memory");
      }
      __builtin_amdgcn_sched_barrier(0);
      __builtin_amdgcn_s_barrier();
      asm volatile("s_waitcnt lgkmcnt(0)" ::: "memory");
      __builtin_amdgcn_sched_barrier(0);
      __builtin_amdgcn_s_setprio(1);
#pragma unroll
      for (int ni = 0; ni < NIF; ++ni) {
        acc[6][ni] = MFMA16(BC8(a00), BC8(bfr[ni][0]), acc[6][ni]);
        acc[6][ni] = MFMA16(BC8(a01), BC8(bfr[ni][1]), acc[6][ni]);
        acc[7][ni] = MFMA16(BC8(a10), BC8(bfr[ni][0]), acc[7][ni]);
        acc[7][ni] = MFMA16(BC8(a11), BC8(bfr[ni][1]), acc[7][ni]);
      }
      __builtin_amdgcn_s_setprio(0);
      __builtin_amdgcn_sched_barrier(0);
      __builtin_amdgcn_s_barrier();
    }
  }

  const int crow0 = m0 + wr * 128;
  const int ccol0 = n0 + wc * (NIF * 16);
#pragma unroll
  for (int mi = 0; mi < 8; ++mi)
#pragma unroll
    for (int ni = 0; ni < NIF; ++ni)
#pragma unroll
      for (int r = 0; r < 4; ++r) {
        const size_t idx =
            (size_t)(crow0 + mi * 16 + g * 4 + r) * N + (ccol0 + ni * 16 + l15);
        if constexpr (OUTF32) ((float*)Cout)[idx] = acc[mi][ni][r];
        else ((unsigned short*)Cout)[idx] = f2bf(acc[mi][ni][r]);
      }
}

// ---------------------------------------------------------------------------
// Flash attention, GQA, causal + sliding window 1024, fused Q-RoPE.
// 1D grid 512, heavy/light decode (R16-exact).
// ---------------------------------------------------------------------------
__global__ __launch_bounds__(512, 2) void attn_kernel(const unsigned short* __restrict__ qkv,
                                                      unsigned short* __restrict__ aout,
                                                      const int* __restrict__ pos) {
  __shared__ __align__(16) unsigned short smem[35840];   // 2 buffers, 70 KiB

  const int tid = threadIdx.x;
  const int lane = tid & 63;
  const int w = tid >> 6;
  const int hi = lane >> 5;
  const int l31 = lane & 31;

  // load-balance decode (qb x h x b), heavy first
  const int bid = blockIdx.x;
  const int half = bid >> 8;             // 0: heavy, 1: light
  const int r_ = bid & 255;
  const int qb = half ? ((r_ & 3) ^ 3) : (4 + (r_ & 3));
  const int h = (r_ >> 2) & 31;
  const int b = r_ >> 7;

  const int q0 = qb * 256;
  const int kh = h >> 2;
  const size_t tokbase = (size_t)b * 2048;
  const int qw0 = q0 + w * 32;
  const int qg = qw0 + l31;

  short8 qf[8];
  {
    const unsigned short* qp = qkv + (tokbase + qg) * 6144 + h * 128;
#pragma unroll
    for (int ks8 = 0; ks8 < 8; ++ks8)
      qf[ks8] = BC8(*(const u32x4*)(qp + ks8 * 16 + hi * 8));
    const float fp = (float)pos[qg];
#pragma unroll
    for (int ks8 = 0; ks8 < 4; ++ks8)
#pragma unroll
      for (int j = 0; j < 8; ++j) {
        const int d = ks8 * 16 + hi * 8 + j;
        const float x1 = bf2f((unsigned short)qf[ks8][j]);
        const float x2 = bf2f((unsigned short)qf[ks8 + 4][j]);
        const float ang = fp * exp2f(-(float)d * 0.2076205059304601f);
        float c, sn;
        __sincosf(ang, &sn, &c);
        qf[ks8][j]     = (short)f2bf(x1 * c - x2 * sn);
        qf[ks8 + 4][j] = (short)f2bf(x2 * c + x1 * sn);
      }
  }

  const int c0key = tid >> 4, c0col = tid & 15;
  const int c1key = (tid + 512) >> 4, c1col = tid & 15;

  u32x4 kreg[2], vreg[2];
  const unsigned short* kvK = qkv + tokbase * 6144 + 4096 + kh * 128;

  const int t0 = (q0 >= 1024 ? (q0 - 1023) >> 6 : 0);
  const int t1 = (q0 + 255) >> 6;

  {
    const unsigned short* kb = kvK + (size_t)(t0 * 64) * 6144;
    kreg[0] = *(const u32x4*)(kb + (size_t)c0key * 6144 + c0col * 8);
    kreg[1] = *(const u32x4*)(kb + (size_t)c1key * 6144 + c1col * 8);
    vreg[0] = *(const u32x4*)(kb + (size_t)c0key * 6144 + 1024 + c0col * 8);
    vreg[1] = *(const u32x4*)(kb + (size_t)c1key * 6144 + 1024 + c1col * 8);
  }

  float m_run = -1e30f, l_run = 0.0f;
  f32x16 o_acc[4] = {};

  for (int kt = t0; kt <= t1; ++kt) {
    const int cur = (kt - t0) & 1;
    unsigned short* kdst = &smem[(cur)*17920];
    unsigned short* vdst = kdst + 8704;

    if (kt == t0) {
      *(u32x4*)&kdst[c0key * 136 + c0col * 8] = kreg[0];
      *(u32x4*)&kdst[c1key * 136 + c1col * 8] = kreg[1];
#pragma unroll
      for (int e = 0; e < 8; ++e) {
        const int e0 = (e + c0col) & 7;
        const int e1 = (e + c1col) & 7;
        vdst[(c0col * 8 + e0) * 72 + c0key] =
            (unsigned short)(vreg[0][e0 >> 1] >> ((e0 & 1) * 16));
        vdst[(c1col * 8 + e1) * 72 + c1key] =
            (unsigned short)(vreg[1][e1 >> 1] >> ((e1 & 1) * 16));
      }
      if (kt < t1) {
        const unsigned short* kb = kvK + (size_t)((kt + 1) * 64) * 6144;
        kreg[0] = *(const u32x4*)(kb + (size_t)c0key * 6144 + c0col * 8);
        kreg[1] = *(const u32x4*)(kb + (size_t)c1key * 6144 + c1col * 8);
        vreg[0] = *(const u32x4*)(kb + (size_t)c0key * 6144 + 1024 + c0col * 8);
        vreg[1] = *(const u32x4*)(kb + (size_t)c1key * 6144 + 1024 + c1col * 8);
      }
      __syncthreads();
    }

    if (kt < t1) {
      unsigned short* kdn = &smem[(cur ^ 1) * 17920];
      unsigned short* vdn = kdn + 8704;
      *(u32x4*)&kdn[c0key * 136 + c0col * 8] = kreg[0];
      *(u32x4*)&kdn[c1key * 136 + c1col * 8] = kreg[1];
#pragma unroll
      for (int e = 0; e < 8; ++e) {
        const int e0 = (e + c0col) & 7;
        const int e1 = (e + c1col) & 7;
        vdn[(c0col * 8 + e0) * 72 + c0key] =
            (unsigned short)(vreg[0][e0 >> 1] >> ((e0 & 1) * 16));
        vdn[(c1col * 8 + e1) * 72 + c1key] =
            (unsigned short)(vreg[1][e1 >> 1] >> ((e1 & 1) * 16));
      }
      if (kt + 2 <= t1) {
        const unsigned short* kb = kvK + (size_t)((kt + 2) * 64) * 6144;
        kreg[0] = *(const u32x4*)(kb + (size_t)c0key * 6144 + c0col * 8);
        kreg[1] = *(const u32x4*)(kb + (size_t)c1key * 6144 + c1col * 8);
        vreg[0] = *(const u32x4*)(kb + (size_t)c0key * 6144 + 1024 + c0col * 8);
        vreg[1] = *(const u32x4*)(kb + (size_t)c1key * 6144 + 1024 + c1col * 8);
      }
    }

    const int ktb = kt * 64;
    if (ktb <= qw0 + 31 && ktb + 63 >= qw0 - 1023) {
      const unsigned short* kb = &smem[cur * 17920];
      const unsigned short* vb = kb + 8704;

      f32x16 s0 = {}, s1 = {};
      const int arow = l31 * 136 + hi * 8;
#pragma unroll
      for (int ks8 = 0; ks8 < 8; ++ks8) {
        u32x4 a0 = *(const u32x4*)&kb[arow + ks8 * 16];
        u32x4 a1 = *(const u32x4*)&kb[arow + 32 * 136 + ks8 * 16];
        s0 = MFMA32(BC8(a0), qf[ks8], s0);
        s1 = MFMA32(BC8(a1), qf[ks8], s1);
      }

      const float scale = 0.08838834764831845f;
      float pv[32];
      const bool need_mask = !(ktb + 63 <= qw0 && ktb >= qw0 - 992);
      if (need_mask) {
#pragma unroll
        for (int r = 0; r < 16; ++r) {
          const int key0 = ktb + ((r & 3) + 8 * (r >> 2) + 4 * hi);
          const int key1 = key0 + 32;
          pv[r]      = (key0 <= qg && qg - key0 < 1024) ? s0[r] * scale : -1e30f;
          pv[16 + r] = (key1 <= qg && qg - key1 < 1024) ? s1[r] * scale : -1e30f;
        }
      } else {
#pragma unroll
        for (int r = 0; r < 16; ++r) {
          pv[r] = s0[r] * scale;
          pv[16 + r] = s1[r] * scale;
        }
      }

      float tm = -1e30f;
#pragma unroll
      for (int i = 0; i < 32; ++i) tm = fmaxf(tm, pv[i]);
      tm = fmaxf(tm, __shfl_xor(tm, 32, 64));
      if (__any(tm > m_run + 8.0f)) {
        const float mn = fmaxf(fmaxf(m_run, tm), -1e20f);
        const float scl = __expf(m_run - mn);
#pragma unroll
        for (int d = 0; d < 4; ++d) o_acc[d] *= scl;
        l_run *= scl;
        m_run = mn;
      }
      float lsum = 0.0f;
#pragma unroll
      for (int i = 0; i < 32; ++i) {
        pv[i] = __expf(pv[i] - m_run);
        lsum += pv[i];
      }
      l_run += lsum + __shfl_xor(lsum, 32, 64);

      u32x4 paf[4];
#pragma unroll
      for (int ks = 0; ks < 4; ++ks) {
        const int base = (ks >> 1) * 16 + (ks & 1) * 8;
        auto rA = __builtin_amdgcn_permlane32_swap(
            (int)cvtpk_bf16(pv[base + 0], pv[base + 1]),
            (int)cvtpk_bf16(pv[base + 4], pv[base + 5]), false, false);
        auto rB = __builtin_amdgcn_permlane32_swap(
            (int)cvtpk_bf16(pv[base + 2], pv[base + 3]),
            (int)cvtpk_bf16(pv[base + 6], pv[base + 7]), false, false);
        paf[ks][0] = (unsigned int)rA[0];
        paf[ks][1] = (unsigned int)rB[0];
        paf[ks][2] = (unsigned int)rA[1];
        paf[ks][3] = (unsigned int)rB[1];
      }

#pragma unroll
      for (int dblk = 0; dblk < 4; ++dblk) {
        const int vrow = (dblk * 32 + l31) * 72 + hi * 8;
#pragma unroll
        for (int ks = 0; ks < 4; ++ks) {
          u32x4 vf = *(const u32x4*)&vb[vrow + ks * 16];
          o_acc[dblk] = MFMA32(BC8(vf), BC8(paf[ks]), o_acc[dblk]);
        }
      }
    }

    __syncthreads();
  }

  const float rl = 1.0f / l_run;
  unsigned short* ob = &smem[w * 4352];
#pragma unroll
  for (int dblk = 0; dblk < 4; ++dblk)
#pragma unroll
    for (int rq = 0; rq < 4; ++rq) {
      u16x4 pk;
#pragma unroll
      for (int i = 0; i < 4; ++i) pk[i] = f2bf(o_acc[dblk][rq * 4 + i] * rl);
      *(u16x4*)&ob[l31 * 136 + dblk * 32 + rq * 8 + hi * 4] = pk;
    }
  __syncthreads();

  const int q0w = q0 + w * 32;
  unsigned short* gout = aout + (tokbase + q0w) * 4096 + h * 128;
#pragma unroll
  for (int r4 = 0; r4 < 8; ++r4) {
    const int row = r4 * 4 + (lane >> 4);
    u32x4 val = *(const u32x4*)&ob[row * 136 + (lane & 15) * 8];
    *(u32x4*)(gout + (size_t)row * 4096 + (lane & 15) * 8) = val;
  }
}

// ---------------------------------------------------------------------------
// launch
// ---------------------------------------------------------------------------
extern "C" void kernel_launch(void* const* d_in, const int* in_sizes, int n_in,
                              void* d_out, int out_size, void* d_ws, size_t ws_size,
                              hipStream_t stream) {
  (void)in_sizes; (void)n_in; (void)out_size; (void)ws_size;
  const float* hs   = (const float*)d_in[0];   // [2,2048,4096]
  const float* wqkv = (const float*)d_in[1];   // [4096,6144]
  const float* wo   = (const float*)d_in[2];   // [4096,4096]
  const int*   pos  = (const int*)d_in[3];     // [2048]
  float* out = (float*)d_out;                  // [2,2048,4096] fp32

  char* ws = (char*)d_ws;
  unsigned short* qkvb = (unsigned short*)ws;                // [4096][6144] bf16
  unsigned short* wT   = (unsigned short*)(ws + 50331648);   // weightT bf16
  unsigned short* hsb  = (unsigned short*)(ws + 100663296);  // [4096][4096] bf16

  cvt1<<<22528, 256, 0, stream>>>(hs, wqkv, hsb, wT);
  // GEMM1: BK=32 tile 256x192, 2 blocks/CU, grid 512 (186.5 us measured)
  gemm_k32<<<512, 512, 0, stream>>>(hsb, wT, qkvb, 4096, 6144, 4096);
  rope_cvtwo<<<12288, 256, 0, stream>>>(qkvb, pos, wo, wT);
  // attn: 1D grid, heavy-then-light order for balanced CU pairing
  attn_kernel<<<512, 512, 0, stream>>>(qkvb, hsb, pos);
  // GEMM2: 8-phase NIF4 256x256, grid 256 = 1.0 CU-wave (~106 us, 1296 TF)
  gemm_p4<4, 1><<<256, 512, 0, stream>>>(hsb, wT, out, 4096, 4096, 4096);
}